// Round 1
// baseline (3837.220 us; speedup 1.0000x reference)
//
#include <hip/hip_runtime.h>

// ---------------- problem constants ----------------
#define T_TOK 4096      // B*S tokens
#define HDIM  2880
#define IDIM  2880
#define NEXP  8
#define TOPK  4

// GEMM tiling: 128x96 block tile (96 divides 2880), BK=32, 4 waves (2x2) of 64x48
#define BM 128
#define BN 96
#define BK 32
#define LDK 40          // padded LDS row length (bf16 elems): 80B stride, kills bank pathology

typedef __attribute__((ext_vector_type(8))) short  s16x8;   // MFMA A/B operand (8 bf16)
typedef __attribute__((ext_vector_type(8))) unsigned short u16x8;
typedef __attribute__((ext_vector_type(4))) unsigned short u16x4;
typedef __attribute__((ext_vector_type(4))) float  f32x4;   // MFMA C/D operand

__device__ __forceinline__ unsigned short f2bf(float f) {
  // round-to-nearest-even f32 -> bf16
  unsigned int u = __float_as_uint(f);
  u += 0x7FFFu + ((u >> 16) & 1u);
  return (unsigned short)(u >> 16);
}

// ---------------- x f32 -> bf16 ----------------
__global__ __launch_bounds__(256) void cvt_kernel(const float* __restrict__ x,
                                                  unsigned short* __restrict__ xb) {
  int i = blockIdx.x * 256 + threadIdx.x;         // one 8-elem chunk per thread
  const f32x4* p = (const f32x4*)x;
  f32x4 a = p[2 * (size_t)i];
  f32x4 b = p[2 * (size_t)i + 1];
  u16x8 o;
  o[0] = f2bf(a[0]); o[1] = f2bf(a[1]); o[2] = f2bf(a[2]); o[3] = f2bf(a[3]);
  o[4] = f2bf(b[0]); o[5] = f2bf(b[1]); o[6] = f2bf(b[2]); o[7] = f2bf(b[3]);
  *(u16x8*)(xb + (size_t)i * 8) = o;
}

// ---------------- router: logits -> top4 -> softmax -> aff (T x 8, zeros elsewhere) ----------------
__global__ __launch_bounds__(256) void router_kernel(const float* __restrict__ x,
                                                     const float* __restrict__ rw,
                                                     const float* __restrict__ rb,
                                                     float* __restrict__ aff) {
  int wave = blockIdx.x * 4 + (threadIdx.x >> 6);  // one wave per token
  int lane = threadIdx.x & 63;
  const float* xr = x + (size_t)wave * HDIM;
  float acc[NEXP];
#pragma unroll
  for (int e = 0; e < NEXP; ++e) acc[e] = 0.f;
  for (int i = lane; i < HDIM; i += 64) {
    float xv = xr[i];
#pragma unroll
    for (int e = 0; e < NEXP; ++e) acc[e] += xv * rw[(size_t)e * HDIM + i];
  }
#pragma unroll
  for (int e = 0; e < NEXP; ++e) {
#pragma unroll
    for (int m = 32; m; m >>= 1) acc[e] += __shfl_xor(acc[e], m);
  }
  if (lane == 0) {
    float lg[NEXP];
#pragma unroll
    for (int e = 0; e < NEXP; ++e) lg[e] = acc[e] + rb[e];
    // top-4, ties -> lowest index first (matches lax.top_k)
    bool used[NEXP];
#pragma unroll
    for (int e = 0; e < NEXP; ++e) used[e] = false;
    int   bi[TOPK];
    float bv[TOPK];
#pragma unroll
    for (int s = 0; s < TOPK; ++s) {
      int best = 0; float vbest = -1e30f;
#pragma unroll
      for (int e = 0; e < NEXP; ++e)
        if (!used[e] && lg[e] > vbest) { vbest = lg[e]; best = e; }
      used[best] = true; bi[s] = best; bv[s] = vbest;
    }
    float mx = bv[0];
    float w[TOPK]; float ssum = 0.f;
#pragma unroll
    for (int s = 0; s < TOPK; ++s) { w[s] = __expf(bv[s] - mx); ssum += w[s]; }
    float o[NEXP];
#pragma unroll
    for (int e = 0; e < NEXP; ++e) o[e] = 0.f;
#pragma unroll
    for (int s = 0; s < TOPK; ++s) o[bi[s]] = w[s] / ssum;
#pragma unroll
    for (int e = 0; e < NEXP; ++e) aff[(size_t)wave * NEXP + e] = o[e];
  }
}

// ---------------- gate/up fused GEMM + SwiGLU + affinity scale -> h (bf16) ----------------
// h[t][n] = aff[t][e] * silu(x@Wg) * (x@Wu)
__global__ __launch_bounds__(256) void gateup_kernel(
    const unsigned short* __restrict__ xb, const float* __restrict__ wg,
    const float* __restrict__ wu, const float* __restrict__ aff,
    unsigned short* __restrict__ h, int expert) {
  __shared__ unsigned short Al[BM * LDK];    // A tile, bf16, padded rows
  __shared__ unsigned short Bgl[BN * LDK];   // Wg tile transposed to [n][k], bf16
  __shared__ unsigned short Bul[BN * LDK];   // Wu tile transposed

  const int tid = threadIdx.x;
  const int m0 = blockIdx.x * BM, n0 = blockIdx.y * BN;
  const int wv = tid >> 6, lane = tid & 63;
  const int msub = (wv >> 1) * 64, nsub = (wv & 1) * 48;
  const int l15 = lane & 15, l4 = lane >> 4;

  const float* wge = wg + (size_t)expert * HDIM * IDIM;
  const float* wue = wu + (size_t)expert * HDIM * IDIM;

  f32x4 accg[4][3]; f32x4 accu[4][3];
#pragma unroll
  for (int mf = 0; mf < 4; ++mf)
#pragma unroll
    for (int nf = 0; nf < 3; ++nf) { accg[mf][nf] = (f32x4)0.f; accu[mf][nf] = (f32x4)0.f; }

  for (int k0 = 0; k0 < HDIM; k0 += BK) {
    // ---- stage A: 128x32 bf16, row-major padded; 2 chunks of 16B per thread
#pragma unroll
    for (int u = 0; u < 2; ++u) {
      int c = tid + u * 256;            // chunk id; row = c>>2, koff = (c&3)*8
      int row = c >> 2, ko = (c & 3) * 8;
      u16x8 v = *(const u16x8*)(xb + (size_t)(m0 + row) * HDIM + (size_t)(k0 + ko));
      *(u16x8*)(&Al[row * LDK + ko]) = v;
    }
    // ---- stage B tiles transposed+converted: unit = (4 k, 1 n); 768 units, 3 per thread
#pragma unroll
    for (int u = 0; u < 3; ++u) {
      int idx = tid + u * 256;
      int n = idx % 96, k4 = idx / 96;  // k4: 0..7
      size_t goff = (size_t)(k0 + k4 * 4) * IDIM + (size_t)(n0 + n);
      const float* pg = wge + goff;
      const float* pu = wue + goff;
      u16x4 vg, vu;
#pragma unroll
      for (int j = 0; j < 4; ++j) {
        vg[j] = f2bf(pg[(size_t)j * IDIM]);
        vu[j] = f2bf(pu[(size_t)j * IDIM]);
      }
      *(u16x4*)(&Bgl[n * LDK + k4 * 4]) = vg;
      *(u16x4*)(&Bul[n * LDK + k4 * 4]) = vu;
    }
    __syncthreads();
    // ---- fragments + MFMA
    s16x8 af[4];
#pragma unroll
    for (int mf = 0; mf < 4; ++mf)
      af[mf] = *(const s16x8*)(&Al[(msub + mf * 16 + l15) * LDK + l4 * 8]);
#pragma unroll
    for (int nf = 0; nf < 3; ++nf) {
      s16x8 bg = *(const s16x8*)(&Bgl[(nsub + nf * 16 + l15) * LDK + l4 * 8]);
      s16x8 bu = *(const s16x8*)(&Bul[(nsub + nf * 16 + l15) * LDK + l4 * 8]);
#pragma unroll
      for (int mf = 0; mf < 4; ++mf) {
        accg[mf][nf] = __builtin_amdgcn_mfma_f32_16x16x32_bf16(af[mf], bg, accg[mf][nf], 0, 0, 0);
        accu[mf][nf] = __builtin_amdgcn_mfma_f32_16x16x32_bf16(af[mf], bu, accu[mf][nf], 0, 0, 0);
      }
    }
    __syncthreads();
  }
  // ---- epilogue: h = aff * silu(g) * u, bf16 store
  float affv[4][4];
#pragma unroll
  for (int mf = 0; mf < 4; ++mf)
#pragma unroll
    for (int r = 0; r < 4; ++r) {
      int trow = m0 + msub + mf * 16 + l4 * 4 + r;
      affv[mf][r] = aff[(size_t)trow * NEXP + expert];
    }
#pragma unroll
  for (int mf = 0; mf < 4; ++mf)
#pragma unroll
    for (int nf = 0; nf < 3; ++nf)
#pragma unroll
      for (int r = 0; r < 4; ++r) {
        float g = accg[mf][nf][r], uu = accu[mf][nf][r];
        float hv = (g / (1.f + __expf(-g))) * uu * affv[mf][r];
        int trow = m0 + msub + mf * 16 + l4 * 4 + r;
        int col = n0 + nsub + nf * 16 + l15;
        h[(size_t)trow * IDIM + col] = f2bf(hv);
      }
}

// ---------------- down GEMM: out += h @ Wd ----------------
__global__ __launch_bounds__(256) void down_kernel(
    const unsigned short* __restrict__ h, const float* __restrict__ wd,
    float* __restrict__ out, int expert) {
  __shared__ unsigned short Al[BM * LDK];
  __shared__ unsigned short Bl[BN * LDK];

  const int tid = threadIdx.x;
  const int m0 = blockIdx.x * BM, n0 = blockIdx.y * BN;
  const int wv = tid >> 6, lane = tid & 63;
  const int msub = (wv >> 1) * 64, nsub = (wv & 1) * 48;
  const int l15 = lane & 15, l4 = lane >> 4;

  const float* wde = wd + (size_t)expert * IDIM * HDIM;

  f32x4 acc[4][3];
#pragma unroll
  for (int mf = 0; mf < 4; ++mf)
#pragma unroll
    for (int nf = 0; nf < 3; ++nf) acc[mf][nf] = (f32x4)0.f;

  for (int k0 = 0; k0 < IDIM; k0 += BK) {
#pragma unroll
    for (int u = 0; u < 2; ++u) {
      int c = tid + u * 256;
      int row = c >> 2, ko = (c & 3) * 8;
      u16x8 v = *(const u16x8*)(h + (size_t)(m0 + row) * IDIM + (size_t)(k0 + ko));
      *(u16x8*)(&Al[row * LDK + ko]) = v;
    }
#pragma unroll
    for (int u = 0; u < 3; ++u) {
      int idx = tid + u * 256;
      int n = idx % 96, k4 = idx / 96;
      size_t goff = (size_t)(k0 + k4 * 4) * HDIM + (size_t)(n0 + n);
      const float* pd = wde + goff;
      u16x4 vd;
#pragma unroll
      for (int j = 0; j < 4; ++j) vd[j] = f2bf(pd[(size_t)j * HDIM]);
      *(u16x4*)(&Bl[n * LDK + k4 * 4]) = vd;
    }
    __syncthreads();
    s16x8 af[4];
#pragma unroll
    for (int mf = 0; mf < 4; ++mf)
      af[mf] = *(const s16x8*)(&Al[(msub + mf * 16 + l15) * LDK + l4 * 8]);
#pragma unroll
    for (int nf = 0; nf < 3; ++nf) {
      s16x8 bb = *(const s16x8*)(&Bl[(nsub + nf * 16 + l15) * LDK + l4 * 8]);
#pragma unroll
      for (int mf = 0; mf < 4; ++mf)
        acc[mf][nf] = __builtin_amdgcn_mfma_f32_16x16x32_bf16(af[mf], bb, acc[mf][nf], 0, 0, 0);
    }
    __syncthreads();
  }
  // accumulate into out (experts serialize on the stream -> no race)
#pragma unroll
  for (int mf = 0; mf < 4; ++mf)
#pragma unroll
    for (int nf = 0; nf < 3; ++nf)
#pragma unroll
      for (int r = 0; r < 4; ++r) {
        int trow = m0 + msub + mf * 16 + l4 * 4 + r;
        int col = n0 + nsub + nf * 16 + l15;
        float* po = out + (size_t)trow * HDIM + col;
        *po = *po + acc[mf][nf][r];
      }
}

// ---------------- launcher ----------------
extern "C" void kernel_launch(void* const* d_in, const int* in_sizes, int n_in,
                              void* d_out, int out_size, void* d_ws, size_t ws_size,
                              hipStream_t stream) {
  (void)in_sizes; (void)n_in; (void)ws_size;
  const float* x  = (const float*)d_in[0];
  const float* rw = (const float*)d_in[1];
  const float* rb = (const float*)d_in[2];
  const float* wg = (const float*)d_in[3];
  const float* wu = (const float*)d_in[4];
  const float* wd = (const float*)d_in[5];
  float* out = (float*)d_out;

  // workspace layout
  char* ws = (char*)d_ws;
  float* aff = (float*)ws;                                        // T*8 f32 = 128KB
  unsigned short* xb = (unsigned short*)(ws + 131072);            // T*H bf16 = 23.6MB
  unsigned short* hb = (unsigned short*)(ws + 131072 + (size_t)T_TOK * HDIM * 2);  // T*I bf16

  hipMemsetAsync(out, 0, (size_t)out_size * sizeof(float), stream);
  cvt_kernel<<<(T_TOK * HDIM / 8) / 256, 256, 0, stream>>>(x, xb);
  router_kernel<<<T_TOK / 4, 256, 0, stream>>>(x, rw, rb, aff);

  for (int e = 0; e < NEXP; ++e) {
    gateup_kernel<<<dim3(T_TOK / BM, IDIM / BN), 256, 0, stream>>>(xb, wg, wu, aff, hb, e);
    down_kernel<<<dim3(T_TOK / BM, HDIM / BN), 256, 0, stream>>>(hb, wd, out, e);
  }
}

// Round 2
// 2768.106 us; speedup vs baseline: 1.3862x; 1.3862x over previous
//
#include <hip/hip_runtime.h>

// ---------------- problem constants ----------------
#define T_TOK 4096      // B*S tokens
#define HDIM  2880
#define IDIM  2880
#define NEXP  8
#define TOPK  4

// GEMM tiling: 128x96 block tile, BK=64, 4 waves (2x2) of 64x48
#define BM 128
#define BN 96
#define BK 64
#define LDK 72          // padded LDS row (bf16 elems): 144B stride = 9*16B, aligned + 2-way-free banks

typedef __attribute__((ext_vector_type(8))) short  s16x8;   // MFMA A/B operand (8 bf16)
typedef __attribute__((ext_vector_type(8))) unsigned short u16x8;
typedef __attribute__((ext_vector_type(4))) float  f32x4;   // MFMA C/D operand

__device__ __forceinline__ unsigned short f2bf(float f) {
  unsigned int u = __float_as_uint(f);
  u += 0x7FFFu + ((u >> 16) & 1u);
  return (unsigned short)(u >> 16);
}

// ---------------- x f32 -> bf16 ----------------
__global__ __launch_bounds__(256) void cvt_kernel(const float* __restrict__ x,
                                                  unsigned short* __restrict__ xb) {
  int i = blockIdx.x * 256 + threadIdx.x;
  const f32x4* p = (const f32x4*)x;
  f32x4 a = p[2 * (size_t)i];
  f32x4 b = p[2 * (size_t)i + 1];
  u16x8 o;
  o[0] = f2bf(a[0]); o[1] = f2bf(a[1]); o[2] = f2bf(a[2]); o[3] = f2bf(a[3]);
  o[4] = f2bf(b[0]); o[5] = f2bf(b[1]); o[6] = f2bf(b[2]); o[7] = f2bf(b[3]);
  *(u16x8*)(xb + (size_t)i * 8) = o;
}

// ---------------- weight transpose+convert: W[k][n] f32 -> Wt[n][k] bf16 ----------------
// 64x64 tiles; grid (45,45,z) with z selecting (s0->d0) or (s1->d1)
__global__ __launch_bounds__(256) void transpose_kernel(const float* __restrict__ s0,
                                                        const float* __restrict__ s1,
                                                        unsigned short* __restrict__ d0,
                                                        unsigned short* __restrict__ d1) {
  __shared__ unsigned short st[64][72];
  const float* src = blockIdx.z ? s1 : s0;
  unsigned short* dst = blockIdx.z ? d1 : d0;
  const int k0 = blockIdx.x * 64, n0 = blockIdx.y * 64;
  const int tid = threadIdx.x;
#pragma unroll
  for (int u = 0; u < 4; ++u) {
    int idx = tid + u * 256;          // 0..1023
    int kr = idx >> 4;                // 0..63
    int nc = (idx & 15) * 4;          // 0..60
    f32x4 v = *(const f32x4*)(src + (size_t)(k0 + kr) * 2880 + (n0 + nc));
#pragma unroll
    for (int j = 0; j < 4; ++j) st[nc + j][kr] = f2bf(v[j]);
  }
  __syncthreads();
  int n = tid >> 2;                   // 0..63
  int kc = (tid & 3) * 16;            // 0,16,32,48
  u16x8 a = *(const u16x8*)(&st[n][kc]);
  u16x8 b = *(const u16x8*)(&st[n][kc + 8]);
  unsigned short* po = dst + (size_t)(n0 + n) * 2880 + (k0 + kc);
  *(u16x8*)(po) = a;
  *(u16x8*)(po + 8) = b;
}

// ---------------- router: logits -> top4 -> softmax -> aff + per-expert token lists ----------------
__global__ __launch_bounds__(256) void router_kernel(const float* __restrict__ x,
                                                     const float* __restrict__ rw,
                                                     const float* __restrict__ rb,
                                                     float* __restrict__ aff,
                                                     int* __restrict__ cnt,
                                                     int* __restrict__ lst) {
  int wave = blockIdx.x * 4 + (threadIdx.x >> 6);  // one wave per token
  int lane = threadIdx.x & 63;
  const float* xr = x + (size_t)wave * HDIM;
  float acc[NEXP];
#pragma unroll
  for (int e = 0; e < NEXP; ++e) acc[e] = 0.f;
  for (int i = lane; i < HDIM; i += 64) {
    float xv = xr[i];
#pragma unroll
    for (int e = 0; e < NEXP; ++e) acc[e] += xv * rw[(size_t)e * HDIM + i];
  }
#pragma unroll
  for (int e = 0; e < NEXP; ++e) {
#pragma unroll
    for (int m = 32; m; m >>= 1) acc[e] += __shfl_xor(acc[e], m);
  }
  if (lane == 0) {
    float lg[NEXP];
#pragma unroll
    for (int e = 0; e < NEXP; ++e) lg[e] = acc[e] + rb[e];
    bool used[NEXP];
#pragma unroll
    for (int e = 0; e < NEXP; ++e) used[e] = false;
    int   bi[TOPK];
    float bv[TOPK];
#pragma unroll
    for (int s = 0; s < TOPK; ++s) {
      int best = 0; float vbest = -1e30f;
#pragma unroll
      for (int e = 0; e < NEXP; ++e)
        if (!used[e] && lg[e] > vbest) { vbest = lg[e]; best = e; }
      used[best] = true; bi[s] = best; bv[s] = vbest;
    }
    float mx = bv[0];
    float w[TOPK]; float ssum = 0.f;
#pragma unroll
    for (int s = 0; s < TOPK; ++s) { w[s] = __expf(bv[s] - mx); ssum += w[s]; }
    float o[NEXP];
#pragma unroll
    for (int e = 0; e < NEXP; ++e) o[e] = 0.f;
#pragma unroll
    for (int s = 0; s < TOPK; ++s) o[bi[s]] = w[s] / ssum;
#pragma unroll
    for (int e = 0; e < NEXP; ++e) aff[(size_t)wave * NEXP + e] = o[e];
#pragma unroll
    for (int s = 0; s < TOPK; ++s) {
      int p = atomicAdd(&cnt[bi[s]], 1);
      lst[bi[s] * T_TOK + p] = wave;
    }
  }
}

// ---------------- gate/up fused GEMM + SwiGLU + affinity scale -> h (bf16, dense token rows) ----------
__global__ __launch_bounds__(256) void gateup_kernel(
    const unsigned short* __restrict__ xb, const unsigned short* __restrict__ wgt,
    const unsigned short* __restrict__ wut, const float* __restrict__ aff,
    const int* __restrict__ lst, const int* __restrict__ cnts,
    unsigned short* __restrict__ h, int expert) {
  const int cnt = cnts[expert];
  const int m0 = blockIdx.x * BM;
  if (m0 >= cnt) return;
  __shared__ unsigned short Al[BM * LDK];
  __shared__ unsigned short Bgl[BN * LDK];
  __shared__ unsigned short Bul[BN * LDK];

  const int tid = threadIdx.x;
  const int n0 = blockIdx.y * BN;
  const int wv = tid >> 6, lane = tid & 63;
  const int msub = (wv >> 1) * 64, nsub = (wv & 1) * 48;
  const int l15 = lane & 15, l4 = lane >> 4;
  const int* mylst = lst + expert * T_TOK;

  // hoist gathered A-row pointers (rows fixed per thread across K-steps)
  const unsigned short* aptr[4];
  int aw[4];
#pragma unroll
  for (int u = 0; u < 4; ++u) {
    int idx = tid + u * 256;          // 0..1023
    int row = idx >> 3, ko = idx & 7;
    int slot = m0 + row;
    int tok = mylst[min(slot, cnt - 1)];
    aptr[u] = xb + (size_t)tok * HDIM + ko * 8;
    aw[u] = row * LDK + ko * 8;
  }
  // hoist B-row pointers
  const unsigned short* bgp[3]; const unsigned short* bup[3]; int bw[3];
#pragma unroll
  for (int u = 0; u < 3; ++u) {
    int idx = tid + u * 256;          // 0..767
    int row = idx >> 3, ko = idx & 7;
    bgp[u] = wgt + (size_t)(n0 + row) * HDIM + ko * 8;
    bup[u] = wut + (size_t)(n0 + row) * HDIM + ko * 8;
    bw[u] = row * LDK + ko * 8;
  }

  f32x4 accg[4][3]; f32x4 accu[4][3];
#pragma unroll
  for (int mf = 0; mf < 4; ++mf)
#pragma unroll
    for (int nf = 0; nf < 3; ++nf) { accg[mf][nf] = (f32x4)0.f; accu[mf][nf] = (f32x4)0.f; }

  for (int k0 = 0; k0 < HDIM; k0 += BK) {
#pragma unroll
    for (int u = 0; u < 4; ++u)
      *(u16x8*)(&Al[aw[u]]) = *(const u16x8*)(aptr[u] + k0);
#pragma unroll
    for (int u = 0; u < 3; ++u) {
      *(u16x8*)(&Bgl[bw[u]]) = *(const u16x8*)(bgp[u] + k0);
      *(u16x8*)(&Bul[bw[u]]) = *(const u16x8*)(bup[u] + k0);
    }
    __syncthreads();
#pragma unroll
    for (int kk = 0; kk < 2; ++kk) {
      s16x8 af[4];
#pragma unroll
      for (int mf = 0; mf < 4; ++mf)
        af[mf] = *(const s16x8*)(&Al[(msub + mf * 16 + l15) * LDK + kk * 32 + l4 * 8]);
#pragma unroll
      for (int nf = 0; nf < 3; ++nf) {
        s16x8 bg = *(const s16x8*)(&Bgl[(nsub + nf * 16 + l15) * LDK + kk * 32 + l4 * 8]);
        s16x8 bu = *(const s16x8*)(&Bul[(nsub + nf * 16 + l15) * LDK + kk * 32 + l4 * 8]);
#pragma unroll
        for (int mf = 0; mf < 4; ++mf) {
          accg[mf][nf] = __builtin_amdgcn_mfma_f32_16x16x32_bf16(af[mf], bg, accg[mf][nf], 0, 0, 0);
          accu[mf][nf] = __builtin_amdgcn_mfma_f32_16x16x32_bf16(af[mf], bu, accu[mf][nf], 0, 0, 0);
        }
      }
    }
    __syncthreads();
  }
  // epilogue: h[tok] = aff * silu(g) * u  (masked to slot < cnt)
#pragma unroll
  for (int mf = 0; mf < 4; ++mf)
#pragma unroll
    for (int r = 0; r < 4; ++r) {
      int slot = m0 + msub + mf * 16 + l4 * 4 + r;
      if (slot < cnt) {
        int tok = mylst[slot];
        float av = aff[(size_t)tok * NEXP + expert];
#pragma unroll
        for (int nf = 0; nf < 3; ++nf) {
          float g = accg[mf][nf][r], uu = accu[mf][nf][r];
          float hv = (g / (1.f + __expf(-g))) * uu * av;
          int col = n0 + nsub + nf * 16 + l15;
          h[(size_t)tok * IDIM + col] = f2bf(hv);
        }
      }
    }
}

// ---------------- down GEMM: out[tok] += h[tok] @ WdT ----------------
__global__ __launch_bounds__(256) void down_kernel(
    const unsigned short* __restrict__ h, const unsigned short* __restrict__ wdt,
    float* __restrict__ out, const int* __restrict__ lst,
    const int* __restrict__ cnts, int expert) {
  const int cnt = cnts[expert];
  const int m0 = blockIdx.x * BM;
  if (m0 >= cnt) return;
  __shared__ unsigned short Al[BM * LDK];
  __shared__ unsigned short Bl[BN * LDK];

  const int tid = threadIdx.x;
  const int n0 = blockIdx.y * BN;
  const int wv = tid >> 6, lane = tid & 63;
  const int msub = (wv >> 1) * 64, nsub = (wv & 1) * 48;
  const int l15 = lane & 15, l4 = lane >> 4;
  const int* mylst = lst + expert * T_TOK;

  const unsigned short* aptr[4]; int aw[4];
#pragma unroll
  for (int u = 0; u < 4; ++u) {
    int idx = tid + u * 256;
    int row = idx >> 3, ko = idx & 7;
    int slot = m0 + row;
    int tok = mylst[min(slot, cnt - 1)];
    aptr[u] = h + (size_t)tok * IDIM + ko * 8;
    aw[u] = row * LDK + ko * 8;
  }
  const unsigned short* bp[3]; int bw[3];
#pragma unroll
  for (int u = 0; u < 3; ++u) {
    int idx = tid + u * 256;
    int row = idx >> 3, ko = idx & 7;
    bp[u] = wdt + (size_t)(n0 + row) * IDIM + ko * 8;
    bw[u] = row * LDK + ko * 8;
  }

  f32x4 acc[4][3];
#pragma unroll
  for (int mf = 0; mf < 4; ++mf)
#pragma unroll
    for (int nf = 0; nf < 3; ++nf) acc[mf][nf] = (f32x4)0.f;

  for (int k0 = 0; k0 < IDIM; k0 += BK) {
#pragma unroll
    for (int u = 0; u < 4; ++u)
      *(u16x8*)(&Al[aw[u]]) = *(const u16x8*)(aptr[u] + k0);
#pragma unroll
    for (int u = 0; u < 3; ++u)
      *(u16x8*)(&Bl[bw[u]]) = *(const u16x8*)(bp[u] + k0);
    __syncthreads();
#pragma unroll
    for (int kk = 0; kk < 2; ++kk) {
      s16x8 af[4];
#pragma unroll
      for (int mf = 0; mf < 4; ++mf)
        af[mf] = *(const s16x8*)(&Al[(msub + mf * 16 + l15) * LDK + kk * 32 + l4 * 8]);
#pragma unroll
      for (int nf = 0; nf < 3; ++nf) {
        s16x8 bb = *(const s16x8*)(&Bl[(nsub + nf * 16 + l15) * LDK + kk * 32 + l4 * 8]);
#pragma unroll
        for (int mf = 0; mf < 4; ++mf)
          acc[mf][nf] = __builtin_amdgcn_mfma_f32_16x16x32_bf16(af[mf], bb, acc[mf][nf], 0, 0, 0);
      }
    }
    __syncthreads();
  }
#pragma unroll
  for (int mf = 0; mf < 4; ++mf)
#pragma unroll
    for (int r = 0; r < 4; ++r) {
      int slot = m0 + msub + mf * 16 + l4 * 4 + r;
      if (slot < cnt) {
        int tok = mylst[slot];
#pragma unroll
        for (int nf = 0; nf < 3; ++nf) {
          int col = n0 + nsub + nf * 16 + l15;
          float* po = out + (size_t)tok * HDIM + col;
          *po = *po + acc[mf][nf][r];
        }
      }
    }
}

// ---------------- launcher ----------------
extern "C" void kernel_launch(void* const* d_in, const int* in_sizes, int n_in,
                              void* d_out, int out_size, void* d_ws, size_t ws_size,
                              hipStream_t stream) {
  (void)in_sizes; (void)n_in; (void)ws_size;
  const float* x  = (const float*)d_in[0];
  const float* rw = (const float*)d_in[1];
  const float* rb = (const float*)d_in[2];
  const float* wg = (const float*)d_in[3];
  const float* wu = (const float*)d_in[4];
  const float* wd = (const float*)d_in[5];
  float* out = (float*)d_out;

  // workspace layout (bytes)
  char* ws = (char*)d_ws;
  float* aff = (float*)ws;                                  // 131072
  int*   cnt = (int*)(ws + 131072);                         // 512
  int*   lst = (int*)(ws + 131584);                         // 8*4096*4 = 131072
  unsigned short* xb  = (unsigned short*)(ws + 327680);     // 23592960
  unsigned short* hb  = (unsigned short*)(ws + 327680 + 23592960ull);           // 23592960
  unsigned short* wgt = (unsigned short*)(ws + 327680 + 2 * 23592960ull);       // 16588800
  unsigned short* wut = (unsigned short*)(ws + 327680 + 2 * 23592960ull + 16588800ull);
  unsigned short* wdt = (unsigned short*)(ws + 327680 + 2 * 23592960ull + 2 * 16588800ull);
  const size_t WSTRIDE = (size_t)HDIM * IDIM;

  hipMemsetAsync(out, 0, (size_t)out_size * sizeof(float), stream);
  hipMemsetAsync(cnt, 0, 512, stream);
  cvt_kernel<<<(T_TOK * HDIM / 8) / 256, 256, 0, stream>>>(x, xb);
  router_kernel<<<T_TOK / 4, 256, 0, stream>>>(x, rw, rb, aff, cnt, lst);

  for (int e = 0; e < NEXP; ++e) {
    transpose_kernel<<<dim3(45, 45, 2), 256, 0, stream>>>(wg + e * WSTRIDE, wu + e * WSTRIDE, wgt, wut);
    gateup_kernel<<<dim3(T_TOK / BM, IDIM / BN), 256, 0, stream>>>(xb, wgt, wut, aff, lst, cnt, hb, e);
    transpose_kernel<<<dim3(45, 45, 1), 256, 0, stream>>>(wd + e * WSTRIDE, wd + e * WSTRIDE, wdt, wdt);
    down_kernel<<<dim3(T_TOK / BM, HDIM / BN), 256, 0, stream>>>(hb, wdt, out, lst, cnt, e);
  }
}

// Round 3
// 2529.616 us; speedup vs baseline: 1.5169x; 1.0943x over previous
//
#include <hip/hip_runtime.h>

// ---------------- problem constants ----------------
#define T_TOK 4096      // B*S tokens
#define HDIM  2880
#define IDIM  2880
#define NEXP  8
#define TOPK  4

// GEMM tiling: 128x96 block tile, BK=64, 4 waves (2x2) of 64x48
// LDS tiles are LINEAR [rows][64] bf16 (128B rows), XOR-swizzled on the k-slot:
//   physical 16B-slot = logical_slot ^ (row & 7)
// global_load_lds writes lane l -> base + l*16 (linear); we pre-swizzle the
// per-lane GLOBAL source address so reads with the swizzle see logical order.
#define BM 128
#define BN 96
#define BK 64

typedef __attribute__((ext_vector_type(8))) short  s16x8;   // MFMA A/B operand (8 bf16)
typedef __attribute__((ext_vector_type(8))) unsigned short u16x8;
typedef __attribute__((ext_vector_type(4))) float  f32x4;   // MFMA C/D operand

__device__ __forceinline__ unsigned short f2bf(float f) {
  unsigned int u = __float_as_uint(f);
  u += 0x7FFFu + ((u >> 16) & 1u);
  return (unsigned short)(u >> 16);
}

__device__ __forceinline__ void gload16(const unsigned short* g, unsigned short* l) {
  __builtin_amdgcn_global_load_lds(
      (const __attribute__((address_space(1))) void*)g,
      (__attribute__((address_space(3))) void*)l, 16, 0, 0);
}

// ---------------- x f32 -> bf16 ----------------
__global__ __launch_bounds__(256) void cvt_kernel(const float* __restrict__ x,
                                                  unsigned short* __restrict__ xb) {
  int i = blockIdx.x * 256 + threadIdx.x;
  const f32x4* p = (const f32x4*)x;
  f32x4 a = p[2 * (size_t)i];
  f32x4 b = p[2 * (size_t)i + 1];
  u16x8 o;
  o[0] = f2bf(a[0]); o[1] = f2bf(a[1]); o[2] = f2bf(a[2]); o[3] = f2bf(a[3]);
  o[4] = f2bf(b[0]); o[5] = f2bf(b[1]); o[6] = f2bf(b[2]); o[7] = f2bf(b[3]);
  *(u16x8*)(xb + (size_t)i * 8) = o;
}

// ---------------- weight transpose+convert: W[k][n] f32 -> Wt[n][k] bf16, 3 mats ----------------
__global__ __launch_bounds__(256) void transpose3_kernel(
    const float* __restrict__ s0, const float* __restrict__ s1, const float* __restrict__ s2,
    unsigned short* __restrict__ d0, unsigned short* __restrict__ d1, unsigned short* __restrict__ d2) {
  __shared__ unsigned short st[64][72];
  const float* src = blockIdx.z == 0 ? s0 : (blockIdx.z == 1 ? s1 : s2);
  unsigned short* dst = blockIdx.z == 0 ? d0 : (blockIdx.z == 1 ? d1 : d2);
  const int k0 = blockIdx.x * 64, n0 = blockIdx.y * 64;
  const int tid = threadIdx.x;
#pragma unroll
  for (int u = 0; u < 4; ++u) {
    int idx = tid + u * 256;          // 0..1023
    int kr = idx >> 4;                // 0..63
    int nc = (idx & 15) * 4;          // 0..60
    f32x4 v = *(const f32x4*)(src + (size_t)(k0 + kr) * 2880 + (n0 + nc));
#pragma unroll
    for (int j = 0; j < 4; ++j) st[nc + j][kr] = f2bf(v[j]);
  }
  __syncthreads();
  int n = tid >> 2;
  int kc = (tid & 3) * 16;
  u16x8 a = *(const u16x8*)(&st[n][kc]);
  u16x8 b = *(const u16x8*)(&st[n][kc + 8]);
  unsigned short* po = dst + (size_t)(n0 + n) * 2880 + (k0 + kc);
  *(u16x8*)(po) = a;
  *(u16x8*)(po + 8) = b;
}

// ---------------- router: logits -> top4 -> softmax -> aff + per-expert token lists ----------------
__global__ __launch_bounds__(256) void router_kernel(const float* __restrict__ x,
                                                     const float* __restrict__ rw,
                                                     const float* __restrict__ rb,
                                                     float* __restrict__ aff,
                                                     int* __restrict__ cnt,
                                                     int* __restrict__ lst) {
  int tok = blockIdx.x * 4 + (threadIdx.x >> 6);   // one wave per token
  int lane = threadIdx.x & 63;
  const float* xr = x + (size_t)tok * HDIM;
  float acc[NEXP];
#pragma unroll
  for (int e = 0; e < NEXP; ++e) acc[e] = 0.f;
  // 720 f32x4 chunks per token; lane handles chunks lane, lane+64, ...
#pragma unroll
  for (int it = 0; it < 12; ++it) {
    int c = it * 64 + lane;
    if (c < 720) {
      f32x4 xv = *(const f32x4*)(xr + c * 4);
#pragma unroll
      for (int e = 0; e < NEXP; ++e) {
        f32x4 wv4 = *(const f32x4*)(rw + (size_t)e * HDIM + c * 4);
        acc[e] += xv[0] * wv4[0] + xv[1] * wv4[1] + xv[2] * wv4[2] + xv[3] * wv4[3];
      }
    }
  }
#pragma unroll
  for (int e = 0; e < NEXP; ++e) {
#pragma unroll
    for (int m = 32; m; m >>= 1) acc[e] += __shfl_xor(acc[e], m);
  }
  if (lane == 0) {
    float lg[NEXP];
#pragma unroll
    for (int e = 0; e < NEXP; ++e) lg[e] = acc[e] + rb[e];
    bool used[NEXP];
#pragma unroll
    for (int e = 0; e < NEXP; ++e) used[e] = false;
    int   bi[TOPK];
    float bv[TOPK];
#pragma unroll
    for (int s = 0; s < TOPK; ++s) {
      int best = 0; float vbest = -1e30f;
#pragma unroll
      for (int e = 0; e < NEXP; ++e)
        if (!used[e] && lg[e] > vbest) { vbest = lg[e]; best = e; }
      used[best] = true; bi[s] = best; bv[s] = vbest;
    }
    float mx = bv[0];
    float w[TOPK]; float ssum = 0.f;
#pragma unroll
    for (int s = 0; s < TOPK; ++s) { w[s] = __expf(bv[s] - mx); ssum += w[s]; }
    float o[NEXP];
#pragma unroll
    for (int e = 0; e < NEXP; ++e) o[e] = 0.f;
#pragma unroll
    for (int s = 0; s < TOPK; ++s) o[bi[s]] = w[s] / ssum;
#pragma unroll
    for (int e = 0; e < NEXP; ++e) aff[(size_t)tok * NEXP + e] = o[e];
#pragma unroll
    for (int s = 0; s < TOPK; ++s) {
      int p = atomicAdd(&cnt[bi[s]], 1);
      lst[bi[s] * T_TOK + p] = tok;
    }
  }
}

// ---------------- gate/up fused GEMM + SwiGLU + affinity scale -> h (bf16) ----------
__global__ __launch_bounds__(256) void gateup_kernel(
    const unsigned short* __restrict__ xb, const unsigned short* __restrict__ wgt,
    const unsigned short* __restrict__ wut, const float* __restrict__ aff,
    const int* __restrict__ lst, const int* __restrict__ cnts,
    unsigned short* __restrict__ h, int expert) {
  const int cnt = cnts[expert];
  const int m0 = blockIdx.x * BM;
  if (m0 >= cnt) return;
  __shared__ __align__(16) unsigned short Al[BM * BK];     // 16KB linear
  __shared__ __align__(16) unsigned short Bgl[BN * BK];    // 12KB
  __shared__ __align__(16) unsigned short Bul[BN * BK];    // 12KB

  const int tid = threadIdx.x;
  const int n0 = blockIdx.y * BN;
  const int wv = tid >> 6, lane = tid & 63;
  const int msub = (wv >> 1) * 64, nsub = (wv & 1) * 48;
  const int l15 = lane & 15, l4 = lane >> 4;
  const int lr = lane >> 3;    // row within 8-row segment
  const int lc = lane & 7;     // 16B slot within row
  const int* mylst = lst + expert * T_TOK;

  // A: 16 segments of (8 rows x 8 slots); wave wv stages segments u*4+wv
  const unsigned short* asrc[4]; unsigned short* adst[4];
#pragma unroll
  for (int u = 0; u < 4; ++u) {
    int s = u * 4 + wv;
    int r = s * 8 + lr;
    int tok = mylst[min(m0 + r, cnt - 1)];
    asrc[u] = xb + (size_t)tok * HDIM + (lc ^ (r & 7)) * 8;   // pre-swizzled source
    adst[u] = &Al[s * 512];                                    // wave-uniform base
  }
  // B: 12 segments each
  const unsigned short* bgsrc[3]; const unsigned short* busrc[3];
  unsigned short* bgdst[3]; unsigned short* budst[3];
#pragma unroll
  for (int u = 0; u < 3; ++u) {
    int s = u * 4 + wv;
    int r = s * 8 + lr;
    size_t off = (size_t)(n0 + r) * HDIM + (size_t)((lc ^ (r & 7)) * 8);
    bgsrc[u] = wgt + off; busrc[u] = wut + off;
    bgdst[u] = &Bgl[s * 512]; budst[u] = &Bul[s * 512];
  }

  f32x4 accg[4][3]; f32x4 accu[4][3];
#pragma unroll
  for (int mf = 0; mf < 4; ++mf)
#pragma unroll
    for (int nf = 0; nf < 3; ++nf) { accg[mf][nf] = (f32x4)0.f; accu[mf][nf] = (f32x4)0.f; }

  for (int k0 = 0; k0 < HDIM; k0 += BK) {
#pragma unroll
    for (int u = 0; u < 4; ++u) gload16(asrc[u] + k0, adst[u]);
#pragma unroll
    for (int u = 0; u < 3; ++u) {
      gload16(bgsrc[u] + k0, bgdst[u]);
      gload16(busrc[u] + k0, budst[u]);
    }
    __syncthreads();   // compiler drains vmcnt before barrier
#pragma unroll
    for (int kk = 0; kk < 2; ++kk) {
      s16x8 af[4];
#pragma unroll
      for (int mf = 0; mf < 4; ++mf) {
        int R = msub + mf * 16 + l15;
        int sl = (kk * 4 + l4) ^ (R & 7);
        af[mf] = *(const s16x8*)(&Al[R * 64 + sl * 8]);
      }
#pragma unroll
      for (int nf = 0; nf < 3; ++nf) {
        int R = nsub + nf * 16 + l15;
        int sl = (kk * 4 + l4) ^ (R & 7);
        s16x8 bg = *(const s16x8*)(&Bgl[R * 64 + sl * 8]);
        s16x8 bu = *(const s16x8*)(&Bul[R * 64 + sl * 8]);
#pragma unroll
        for (int mf = 0; mf < 4; ++mf) {
          accg[mf][nf] = __builtin_amdgcn_mfma_f32_16x16x32_bf16(af[mf], bg, accg[mf][nf], 0, 0, 0);
          accu[mf][nf] = __builtin_amdgcn_mfma_f32_16x16x32_bf16(af[mf], bu, accu[mf][nf], 0, 0, 0);
        }
      }
    }
    __syncthreads();
  }
  // epilogue: h[tok] = aff * silu(g) * u  (masked to slot < cnt)
#pragma unroll
  for (int mf = 0; mf < 4; ++mf)
#pragma unroll
    for (int r = 0; r < 4; ++r) {
      int slot = m0 + msub + mf * 16 + l4 * 4 + r;
      if (slot < cnt) {
        int tok = mylst[slot];
        float av = aff[(size_t)tok * NEXP + expert];
#pragma unroll
        for (int nf = 0; nf < 3; ++nf) {
          float g = accg[mf][nf][r], uu = accu[mf][nf][r];
          float hv = (g / (1.f + __expf(-g))) * uu * av;
          int col = n0 + nsub + nf * 16 + l15;
          h[(size_t)tok * IDIM + col] = f2bf(hv);
        }
      }
    }
}

// ---------------- down GEMM: out[tok] += h[tok] @ WdT ----------------
__global__ __launch_bounds__(256) void down_kernel(
    const unsigned short* __restrict__ h, const unsigned short* __restrict__ wdt,
    float* __restrict__ out, const int* __restrict__ lst,
    const int* __restrict__ cnts, int expert) {
  const int cnt = cnts[expert];
  const int m0 = blockIdx.x * BM;
  if (m0 >= cnt) return;
  __shared__ __align__(16) unsigned short Al[BM * BK];
  __shared__ __align__(16) unsigned short Bl[BN * BK];

  const int tid = threadIdx.x;
  const int n0 = blockIdx.y * BN;
  const int wv = tid >> 6, lane = tid & 63;
  const int msub = (wv >> 1) * 64, nsub = (wv & 1) * 48;
  const int l15 = lane & 15, l4 = lane >> 4;
  const int lr = lane >> 3, lc = lane & 7;
  const int* mylst = lst + expert * T_TOK;

  const unsigned short* asrc[4]; unsigned short* adst[4];
#pragma unroll
  for (int u = 0; u < 4; ++u) {
    int s = u * 4 + wv;
    int r = s * 8 + lr;
    int tok = mylst[min(m0 + r, cnt - 1)];
    asrc[u] = h + (size_t)tok * IDIM + (lc ^ (r & 7)) * 8;
    adst[u] = &Al[s * 512];
  }
  const unsigned short* bsrc[3]; unsigned short* bdst[3];
#pragma unroll
  for (int u = 0; u < 3; ++u) {
    int s = u * 4 + wv;
    int r = s * 8 + lr;
    bsrc[u] = wdt + (size_t)(n0 + r) * IDIM + (size_t)((lc ^ (r & 7)) * 8);
    bdst[u] = &Bl[s * 512];
  }

  f32x4 acc[4][3];
#pragma unroll
  for (int mf = 0; mf < 4; ++mf)
#pragma unroll
    for (int nf = 0; nf < 3; ++nf) acc[mf][nf] = (f32x4)0.f;

  for (int k0 = 0; k0 < IDIM; k0 += BK) {
#pragma unroll
    for (int u = 0; u < 4; ++u) gload16(asrc[u] + k0, adst[u]);
#pragma unroll
    for (int u = 0; u < 3; ++u) gload16(bsrc[u] + k0, bdst[u]);
    __syncthreads();
#pragma unroll
    for (int kk = 0; kk < 2; ++kk) {
      s16x8 af[4];
#pragma unroll
      for (int mf = 0; mf < 4; ++mf) {
        int R = msub + mf * 16 + l15;
        int sl = (kk * 4 + l4) ^ (R & 7);
        af[mf] = *(const s16x8*)(&Al[R * 64 + sl * 8]);
      }
#pragma unroll
      for (int nf = 0; nf < 3; ++nf) {
        int R = nsub + nf * 16 + l15;
        int sl = (kk * 4 + l4) ^ (R & 7);
        s16x8 bb = *(const s16x8*)(&Bl[R * 64 + sl * 8]);
#pragma unroll
        for (int mf = 0; mf < 4; ++mf)
          acc[mf][nf] = __builtin_amdgcn_mfma_f32_16x16x32_bf16(af[mf], bb, acc[mf][nf], 0, 0, 0);
      }
    }
    __syncthreads();
  }
#pragma unroll
  for (int mf = 0; mf < 4; ++mf)
#pragma unroll
    for (int r = 0; r < 4; ++r) {
      int slot = m0 + msub + mf * 16 + l4 * 4 + r;
      if (slot < cnt) {
        int tok = mylst[slot];
#pragma unroll
        for (int nf = 0; nf < 3; ++nf) {
          int col = n0 + nsub + nf * 16 + l15;
          float* po = out + (size_t)tok * HDIM + col;
          *po = *po + acc[mf][nf][r];
        }
      }
    }
}

// ---------------- launcher ----------------
extern "C" void kernel_launch(void* const* d_in, const int* in_sizes, int n_in,
                              void* d_out, int out_size, void* d_ws, size_t ws_size,
                              hipStream_t stream) {
  (void)in_sizes; (void)n_in; (void)ws_size;
  const float* x  = (const float*)d_in[0];
  const float* rw = (const float*)d_in[1];
  const float* rb = (const float*)d_in[2];
  const float* wg = (const float*)d_in[3];
  const float* wu = (const float*)d_in[4];
  const float* wd = (const float*)d_in[5];
  float* out = (float*)d_out;

  // workspace layout (bytes)
  char* ws = (char*)d_ws;
  float* aff = (float*)ws;                                  // 131072
  int*   cnt = (int*)(ws + 131072);                         // 512
  int*   lst = (int*)(ws + 131584);                         // 131072
  unsigned short* xb  = (unsigned short*)(ws + 327680);     // 23592960
  unsigned short* hb  = (unsigned short*)(ws + 327680 + 23592960ull);
  unsigned short* wgt = (unsigned short*)(ws + 327680 + 2 * 23592960ull);
  unsigned short* wut = (unsigned short*)(ws + 327680 + 2 * 23592960ull + 16588800ull);
  unsigned short* wdt = (unsigned short*)(ws + 327680 + 2 * 23592960ull + 2 * 16588800ull);
  const size_t WSTRIDE = (size_t)HDIM * IDIM;

  hipMemsetAsync(out, 0, (size_t)out_size * sizeof(float), stream);
  hipMemsetAsync(cnt, 0, 512, stream);
  cvt_kernel<<<(T_TOK * HDIM / 8) / 256, 256, 0, stream>>>(x, xb);
  router_kernel<<<T_TOK / 4, 256, 0, stream>>>(x, rw, rb, aff, cnt, lst);

  for (int e = 0; e < NEXP; ++e) {
    transpose3_kernel<<<dim3(45, 45, 3), 256, 0, stream>>>(
        wg + e * WSTRIDE, wu + e * WSTRIDE, wd + e * WSTRIDE, wgt, wut, wdt);
    gateup_kernel<<<dim3(T_TOK / BM, IDIM / BN), 256, 0, stream>>>(xb, wgt, wut, aff, lst, cnt, hb, e);
    down_kernel<<<dim3(T_TOK / BM, HDIM / BN), 256, 0, stream>>>(hb, wdt, out, lst, cnt, e);
  }
}

// Round 4
// 2497.936 us; speedup vs baseline: 1.5362x; 1.0127x over previous
//
#include <hip/hip_runtime.h>

// ---------------- problem constants ----------------
#define T_TOK 4096      // B*S tokens
#define HDIM  2880
#define IDIM  2880
#define NEXP  8
#define TOPK  4

// GEMM tiling: 128x96 block tile, BK=64, 4 waves (2x2) of 64x48.
// LDS tiles LINEAR [row][64] bf16 (128B rows), XOR-swizzled on the 16B k-slot:
//   physical_slot = logical_slot ^ (row & 7)
// global_load_lds writes lane l -> base + l*16 (linear); per-lane GLOBAL source
// is pre-swizzled so swizzled reads see logical order (both-sides involution).
// Double-buffered: stage(next) issued BEFORE compute(cur); one barrier/step.
#define BM 128
#define BN 96
#define BK 64
#define ASZ (BM * BK)   // 8192 elems / 16 KB per buffer
#define BSZ (BN * BK)   // 6144 elems / 12 KB per buffer
#define NSTEP 45        // 2880 / 64

typedef __attribute__((ext_vector_type(8))) short  s16x8;   // MFMA A/B operand (8 bf16)
typedef __attribute__((ext_vector_type(8))) unsigned short u16x8;
typedef __attribute__((ext_vector_type(4))) float  f32x4;   // MFMA C/D operand

__device__ __forceinline__ unsigned short f2bf(float f) {
  unsigned int u = __float_as_uint(f);
  u += 0x7FFFu + ((u >> 16) & 1u);
  return (unsigned short)(u >> 16);
}

__device__ __forceinline__ void gload16(const unsigned short* g, unsigned short* l) {
  __builtin_amdgcn_global_load_lds(
      (const __attribute__((address_space(1))) void*)g,
      (__attribute__((address_space(3))) void*)l, 16, 0, 0);
}

// ---------------- x f32 -> bf16 ----------------
__global__ __launch_bounds__(256) void cvt_kernel(const float* __restrict__ x,
                                                  unsigned short* __restrict__ xb) {
  int i = blockIdx.x * 256 + threadIdx.x;
  const f32x4* p = (const f32x4*)x;
  f32x4 a = p[2 * (size_t)i];
  f32x4 b = p[2 * (size_t)i + 1];
  u16x8 o;
  o[0] = f2bf(a[0]); o[1] = f2bf(a[1]); o[2] = f2bf(a[2]); o[3] = f2bf(a[3]);
  o[4] = f2bf(b[0]); o[5] = f2bf(b[1]); o[6] = f2bf(b[2]); o[7] = f2bf(b[3]);
  *(u16x8*)(xb + (size_t)i * 8) = o;
}

// ---------------- weight transpose+convert: W[k][n] f32 -> Wt[n][k] bf16, 3 mats ----------------
__global__ __launch_bounds__(256) void transpose3_kernel(
    const float* __restrict__ s0, const float* __restrict__ s1, const float* __restrict__ s2,
    unsigned short* __restrict__ d0, unsigned short* __restrict__ d1, unsigned short* __restrict__ d2) {
  __shared__ unsigned short st[64][72];
  const float* src = blockIdx.z == 0 ? s0 : (blockIdx.z == 1 ? s1 : s2);
  unsigned short* dst = blockIdx.z == 0 ? d0 : (blockIdx.z == 1 ? d1 : d2);
  const int k0 = blockIdx.x * 64, n0 = blockIdx.y * 64;
  const int tid = threadIdx.x;
#pragma unroll
  for (int u = 0; u < 4; ++u) {
    int idx = tid + u * 256;
    int kr = idx >> 4;
    int nc = (idx & 15) * 4;
    f32x4 v = *(const f32x4*)(src + (size_t)(k0 + kr) * 2880 + (n0 + nc));
#pragma unroll
    for (int j = 0; j < 4; ++j) st[nc + j][kr] = f2bf(v[j]);
  }
  __syncthreads();
  int n = tid >> 2;
  int kc = (tid & 3) * 16;
  u16x8 a = *(const u16x8*)(&st[n][kc]);
  u16x8 b = *(const u16x8*)(&st[n][kc + 8]);
  unsigned short* po = dst + (size_t)(n0 + n) * 2880 + (k0 + kc);
  *(u16x8*)(po) = a;
  *(u16x8*)(po + 8) = b;
}

// ---------------- router: 8 tokens/wave, w-chunks reused across tokens ----------------
__global__ __launch_bounds__(256) void router_kernel(const float* __restrict__ x,
                                                     const float* __restrict__ rw,
                                                     const float* __restrict__ rb,
                                                     float* __restrict__ aff,
                                                     int* __restrict__ cnt,
                                                     int* __restrict__ lst) {
  const int wv = threadIdx.x >> 6, lane = threadIdx.x & 63;
  const int tok0 = (blockIdx.x * 4 + wv) * 8;
  float acc[8][NEXP];
#pragma unroll
  for (int t = 0; t < 8; ++t)
#pragma unroll
    for (int e = 0; e < NEXP; ++e) acc[t][e] = 0.f;

#pragma unroll
  for (int it = 0; it < 12; ++it) {
    int c = it * 64 + lane;               // 16B chunk id, 720 per row
    if (c < 720) {
      f32x4 w4[NEXP];
#pragma unroll
      for (int e = 0; e < NEXP; ++e)
        w4[e] = *(const f32x4*)(rw + (size_t)e * HDIM + c * 4);
#pragma unroll
      for (int t = 0; t < 8; ++t) {
        f32x4 xv = *(const f32x4*)(x + (size_t)(tok0 + t) * HDIM + c * 4);
#pragma unroll
        for (int e = 0; e < NEXP; ++e)
          acc[t][e] += xv[0] * w4[e][0] + xv[1] * w4[e][1] + xv[2] * w4[e][2] + xv[3] * w4[e][3];
      }
    }
  }
  // butterfly: all lanes end with full sums
#pragma unroll
  for (int t = 0; t < 8; ++t)
#pragma unroll
    for (int e = 0; e < NEXP; ++e) {
#pragma unroll
      for (int m = 32; m; m >>= 1) acc[t][e] += __shfl_xor(acc[t][e], m);
    }
  if (lane < 8) {
    int tok = tok0 + lane;
    float lg[NEXP];
#pragma unroll
    for (int e = 0; e < NEXP; ++e) lg[e] = acc[lane][e] + rb[e];
    bool used[NEXP];
#pragma unroll
    for (int e = 0; e < NEXP; ++e) used[e] = false;
    int bi[TOPK]; float bv[TOPK];
#pragma unroll
    for (int s = 0; s < TOPK; ++s) {
      int best = 0; float vbest = -1e30f;
#pragma unroll
      for (int e = 0; e < NEXP; ++e)
        if (!used[e] && lg[e] > vbest) { vbest = lg[e]; best = e; }
      used[best] = true; bi[s] = best; bv[s] = vbest;
    }
    float mx = bv[0];
    float w[TOPK]; float ssum = 0.f;
#pragma unroll
    for (int s = 0; s < TOPK; ++s) { w[s] = __expf(bv[s] - mx); ssum += w[s]; }
    float o[NEXP];
#pragma unroll
    for (int e = 0; e < NEXP; ++e) o[e] = 0.f;
#pragma unroll
    for (int s = 0; s < TOPK; ++s) o[bi[s]] = w[s] / ssum;
#pragma unroll
    for (int e = 0; e < NEXP; ++e) aff[(size_t)tok * NEXP + e] = o[e];
#pragma unroll
    for (int s = 0; s < TOPK; ++s) {
      int p = atomicAdd(&cnt[bi[s]], 1);
      lst[bi[s] * T_TOK + p] = tok;
    }
  }
}

// ---------------- gate/up fused GEMM + SwiGLU + affinity scale -> h (bf16) ----------
__global__ __launch_bounds__(256) void gateup_kernel(
    const unsigned short* __restrict__ xb, const unsigned short* __restrict__ wgt,
    const unsigned short* __restrict__ wut, const float* __restrict__ aff,
    const int* __restrict__ lst, const int* __restrict__ cnts,
    unsigned short* __restrict__ h, int expert) {
  const int cnt = cnts[expert];
  const int m0 = blockIdx.x * BM;
  if (m0 >= cnt) return;
  __shared__ __align__(16) unsigned short Al[2 * ASZ];    // 32KB
  __shared__ __align__(16) unsigned short Bgl[2 * BSZ];   // 24KB
  __shared__ __align__(16) unsigned short Bul[2 * BSZ];   // 24KB

  const int tid = threadIdx.x;
  const int n0 = blockIdx.y * BN;
  const int wv = tid >> 6, lane = tid & 63;
  const int msub = (wv >> 1) * 64, nsub = (wv & 1) * 48;
  const int l15 = lane & 15, l4 = lane >> 4;
  const int lr = lane >> 3, lc = lane & 7;
  const int* mylst = lst + expert * T_TOK;

  const unsigned short* asrc[4]; unsigned short* adst[4];
#pragma unroll
  for (int u = 0; u < 4; ++u) {
    int s = u * 4 + wv;
    int r = s * 8 + lr;
    int tok = mylst[min(m0 + r, cnt - 1)];
    asrc[u] = xb + (size_t)tok * HDIM + (lc ^ (r & 7)) * 8;
    adst[u] = &Al[s * 512];
  }
  const unsigned short* bgsrc[3]; const unsigned short* busrc[3];
  unsigned short* bgdst[3]; unsigned short* budst[3];
#pragma unroll
  for (int u = 0; u < 3; ++u) {
    int s = u * 4 + wv;
    int r = s * 8 + lr;
    size_t off = (size_t)(n0 + r) * HDIM + (size_t)((lc ^ (r & 7)) * 8);
    bgsrc[u] = wgt + off; busrc[u] = wut + off;
    bgdst[u] = &Bgl[s * 512]; budst[u] = &Bul[s * 512];
  }

  f32x4 accg[4][3]; f32x4 accu[4][3];
#pragma unroll
  for (int mf = 0; mf < 4; ++mf)
#pragma unroll
    for (int nf = 0; nf < 3; ++nf) { accg[mf][nf] = (f32x4)0.f; accu[mf][nf] = (f32x4)0.f; }

  auto stage = [&](int buf, int k0) {
    int bo = buf ? ASZ : 0;
#pragma unroll
    for (int u = 0; u < 4; ++u) gload16(asrc[u] + k0, adst[u] + bo);
    int bb = buf ? BSZ : 0;
#pragma unroll
    for (int u = 0; u < 3; ++u) {
      gload16(bgsrc[u] + k0, bgdst[u] + bb);
      gload16(busrc[u] + k0, budst[u] + bb);
    }
  };
  auto compute = [&](int buf) {
    const unsigned short* Ab = Al + (buf ? ASZ : 0);
    const unsigned short* Bg = Bgl + (buf ? BSZ : 0);
    const unsigned short* Bu = Bul + (buf ? BSZ : 0);
#pragma unroll
    for (int kk = 0; kk < 2; ++kk) {
      s16x8 af[4];
#pragma unroll
      for (int mf = 0; mf < 4; ++mf) {
        int R = msub + mf * 16 + l15;
        int sl = (kk * 4 + l4) ^ (R & 7);
        af[mf] = *(const s16x8*)(&Ab[R * 64 + sl * 8]);
      }
#pragma unroll
      for (int nf = 0; nf < 3; ++nf) {
        int R = nsub + nf * 16 + l15;
        int sl = (kk * 4 + l4) ^ (R & 7);
        s16x8 bg = *(const s16x8*)(&Bg[R * 64 + sl * 8]);
        s16x8 bu = *(const s16x8*)(&Bu[R * 64 + sl * 8]);
#pragma unroll
        for (int mf = 0; mf < 4; ++mf) {
          accg[mf][nf] = __builtin_amdgcn_mfma_f32_16x16x32_bf16(af[mf], bg, accg[mf][nf], 0, 0, 0);
          accu[mf][nf] = __builtin_amdgcn_mfma_f32_16x16x32_bf16(af[mf], bu, accu[mf][nf], 0, 0, 0);
        }
      }
    }
  };

  stage(0, 0);
  __syncthreads();
#pragma unroll 1
  for (int step = 0; step < NSTEP - 1; ++step) {
    stage((step & 1) ^ 1, (step + 1) * BK);   // prefetch next tile (other buffer)
    asm volatile("" ::: "memory");
    compute(step & 1);                         // MFMA on current buffer
    __syncthreads();                           // drains vmcnt+lgkm for all waves
  }
  compute((NSTEP - 1) & 1);

#pragma unroll
  for (int mf = 0; mf < 4; ++mf)
#pragma unroll
    for (int r = 0; r < 4; ++r) {
      int slot = m0 + msub + mf * 16 + l4 * 4 + r;
      if (slot < cnt) {
        int tok = mylst[slot];
        float av = aff[(size_t)tok * NEXP + expert];
#pragma unroll
        for (int nf = 0; nf < 3; ++nf) {
          float g = accg[mf][nf][r], uu = accu[mf][nf][r];
          float hv = (g / (1.f + __expf(-g))) * uu * av;
          int col = n0 + nsub + nf * 16 + l15;
          h[(size_t)tok * IDIM + col] = f2bf(hv);
        }
      }
    }
}

// ---------------- down GEMM: out[tok] += h[tok] @ WdT ----------------
__global__ __launch_bounds__(256) void down_kernel(
    const unsigned short* __restrict__ h, const unsigned short* __restrict__ wdt,
    float* __restrict__ out, const int* __restrict__ lst,
    const int* __restrict__ cnts, int expert) {
  const int cnt = cnts[expert];
  const int m0 = blockIdx.x * BM;
  if (m0 >= cnt) return;
  __shared__ __align__(16) unsigned short Al[2 * ASZ];
  __shared__ __align__(16) unsigned short Bl[2 * BSZ];

  const int tid = threadIdx.x;
  const int n0 = blockIdx.y * BN;
  const int wv = tid >> 6, lane = tid & 63;
  const int msub = (wv >> 1) * 64, nsub = (wv & 1) * 48;
  const int l15 = lane & 15, l4 = lane >> 4;
  const int lr = lane >> 3, lc = lane & 7;
  const int* mylst = lst + expert * T_TOK;

  const unsigned short* asrc[4]; unsigned short* adst[4];
#pragma unroll
  for (int u = 0; u < 4; ++u) {
    int s = u * 4 + wv;
    int r = s * 8 + lr;
    int tok = mylst[min(m0 + r, cnt - 1)];
    asrc[u] = h + (size_t)tok * IDIM + (lc ^ (r & 7)) * 8;
    adst[u] = &Al[s * 512];
  }
  const unsigned short* bsrc[3]; unsigned short* bdst[3];
#pragma unroll
  for (int u = 0; u < 3; ++u) {
    int s = u * 4 + wv;
    int r = s * 8 + lr;
    bsrc[u] = wdt + (size_t)(n0 + r) * IDIM + (size_t)((lc ^ (r & 7)) * 8);
    bdst[u] = &Bl[s * 512];
  }

  f32x4 acc[4][3];
#pragma unroll
  for (int mf = 0; mf < 4; ++mf)
#pragma unroll
    for (int nf = 0; nf < 3; ++nf) acc[mf][nf] = (f32x4)0.f;

  auto stage = [&](int buf, int k0) {
    int bo = buf ? ASZ : 0;
#pragma unroll
    for (int u = 0; u < 4; ++u) gload16(asrc[u] + k0, adst[u] + bo);
    int bb = buf ? BSZ : 0;
#pragma unroll
    for (int u = 0; u < 3; ++u) gload16(bsrc[u] + k0, bdst[u] + bb);
  };
  auto compute = [&](int buf) {
    const unsigned short* Ab = Al + (buf ? ASZ : 0);
    const unsigned short* Bb = Bl + (buf ? BSZ : 0);
#pragma unroll
    for (int kk = 0; kk < 2; ++kk) {
      s16x8 af[4];
#pragma unroll
      for (int mf = 0; mf < 4; ++mf) {
        int R = msub + mf * 16 + l15;
        int sl = (kk * 4 + l4) ^ (R & 7);
        af[mf] = *(const s16x8*)(&Ab[R * 64 + sl * 8]);
      }
#pragma unroll
      for (int nf = 0; nf < 3; ++nf) {
        int R = nsub + nf * 16 + l15;
        int sl = (kk * 4 + l4) ^ (R & 7);
        s16x8 bb = *(const s16x8*)(&Bb[R * 64 + sl * 8]);
#pragma unroll
        for (int mf = 0; mf < 4; ++mf)
          acc[mf][nf] = __builtin_amdgcn_mfma_f32_16x16x32_bf16(af[mf], bb, acc[mf][nf], 0, 0, 0);
      }
    }
  };

  stage(0, 0);
  __syncthreads();
#pragma unroll 1
  for (int step = 0; step < NSTEP - 1; ++step) {
    stage((step & 1) ^ 1, (step + 1) * BK);
    asm volatile("" ::: "memory");
    compute(step & 1);
    __syncthreads();
  }
  compute((NSTEP - 1) & 1);

#pragma unroll
  for (int mf = 0; mf < 4; ++mf)
#pragma unroll
    for (int r = 0; r < 4; ++r) {
      int slot = m0 + msub + mf * 16 + l4 * 4 + r;
      if (slot < cnt) {
        int tok = mylst[slot];
#pragma unroll
        for (int nf = 0; nf < 3; ++nf) {
          int col = n0 + nsub + nf * 16 + l15;
          float* po = out + (size_t)tok * HDIM + col;
          *po = *po + acc[mf][nf][r];
        }
      }
    }
}

// ---------------- launcher ----------------
extern "C" void kernel_launch(void* const* d_in, const int* in_sizes, int n_in,
                              void* d_out, int out_size, void* d_ws, size_t ws_size,
                              hipStream_t stream) {
  (void)in_sizes; (void)n_in; (void)ws_size;
  const float* x  = (const float*)d_in[0];
  const float* rw = (const float*)d_in[1];
  const float* rb = (const float*)d_in[2];
  const float* wg = (const float*)d_in[3];
  const float* wu = (const float*)d_in[4];
  const float* wd = (const float*)d_in[5];
  float* out = (float*)d_out;

  // workspace layout (bytes)
  char* ws = (char*)d_ws;
  float* aff = (float*)ws;                                  // 131072
  int*   cnt = (int*)(ws + 131072);                         // 512
  int*   lst = (int*)(ws + 131584);                         // 131072
  unsigned short* xb  = (unsigned short*)(ws + 327680);     // 23592960
  unsigned short* hb  = (unsigned short*)(ws + 327680 + 23592960ull);
  unsigned short* wgt = (unsigned short*)(ws + 327680 + 2 * 23592960ull);
  unsigned short* wut = (unsigned short*)(ws + 327680 + 2 * 23592960ull + 16588800ull);
  unsigned short* wdt = (unsigned short*)(ws + 327680 + 2 * 23592960ull + 2 * 16588800ull);
  const size_t WSTRIDE = (size_t)HDIM * IDIM;

  hipMemsetAsync(out, 0, (size_t)out_size * sizeof(float), stream);
  hipMemsetAsync(cnt, 0, 512, stream);
  cvt_kernel<<<(T_TOK * HDIM / 8) / 256, 256, 0, stream>>>(x, xb);
  router_kernel<<<T_TOK / 32, 256, 0, stream>>>(x, rw, rb, aff, cnt, lst);

  for (int e = 0; e < NEXP; ++e) {
    transpose3_kernel<<<dim3(45, 45, 3), 256, 0, stream>>>(
        wg + e * WSTRIDE, wu + e * WSTRIDE, wd + e * WSTRIDE, wgt, wut, wdt);
    gateup_kernel<<<dim3(T_TOK / BM, IDIM / BN), 256, 0, stream>>>(xb, wgt, wut, aff, lst, cnt, hb, e);
    down_kernel<<<dim3(T_TOK / BM, HDIM / BN), 256, 0, stream>>>(hb, wdt, out, lst, cnt, e);
  }
}

// Round 5
// 1462.801 us; speedup vs baseline: 2.6232x; 1.7076x over previous
//
#include <hip/hip_runtime.h>

// ---------------- problem constants ----------------
#define T_TOK 4096      // B*S tokens
#define HDIM  2880
#define IDIM  2880
#define NEXP  8
#define TOPK  4
#define WEL   (2880 * 2880)   // elems per weight matrix

// GEMM tiling: 128x96 block tile, BK=64, 4 waves (2x2) of 64x48.
// LDS tiles LINEAR [row][64] bf16 (128B rows), XOR-swizzled on the 16B k-slot:
//   physical_slot = logical_slot ^ (row & 7)
// global_load_lds writes lane l -> base + l*16 (linear); per-lane GLOBAL source
// is pre-swizzled so swizzled reads see logical order (both-sides involution).
// Single-buffered (40KB gateup / 28KB down) -> 4 blocks/CU; rely on inter-block
// wave overlap (m114) instead of dbuf (measured zero at 2 blocks/CU).
#define BM 128
#define BN 96
#define BK 64
#define NSTEP 45        // 2880 / 64

typedef __attribute__((ext_vector_type(8))) short  s16x8;
typedef __attribute__((ext_vector_type(8))) unsigned short u16x8;
typedef __attribute__((ext_vector_type(4))) float  f32x4;

__device__ __forceinline__ unsigned short f2bf(float f) {
  unsigned int u = __float_as_uint(f);
  u += 0x7FFFu + ((u >> 16) & 1u);
  return (unsigned short)(u >> 16);
}

__device__ __forceinline__ void gload16(const unsigned short* g, unsigned short* l) {
  __builtin_amdgcn_global_load_lds(
      (const __attribute__((address_space(1))) void*)g,
      (__attribute__((address_space(3))) void*)l, 16, 0, 0);
}

// ---------------- x f32 -> bf16 ----------------
__global__ __launch_bounds__(256) void cvt_kernel(const float* __restrict__ x,
                                                  unsigned short* __restrict__ xb) {
  int i = blockIdx.x * 256 + threadIdx.x;
  const f32x4* p = (const f32x4*)x;
  f32x4 a = p[2 * (size_t)i];
  f32x4 b = p[2 * (size_t)i + 1];
  u16x8 o;
  o[0] = f2bf(a[0]); o[1] = f2bf(a[1]); o[2] = f2bf(a[2]); o[3] = f2bf(a[3]);
  o[4] = f2bf(b[0]); o[5] = f2bf(b[1]); o[6] = f2bf(b[2]); o[7] = f2bf(b[3]);
  *(u16x8*)(xb + (size_t)i * 8) = o;
}

// ---------------- weight transpose+convert for a group of G experts ----------------
// z = j*3 + m : expert-local j, matrix m (0=wg, 1=wu, 2=wd)
__global__ __launch_bounds__(256) void transpose_group_kernel(
    const float* __restrict__ wg, const float* __restrict__ wu,
    const float* __restrict__ wd, unsigned short* __restrict__ wbuf, int ge) {
  __shared__ unsigned short st[64][72];
  const int z = blockIdx.z, j = z / 3, m = z % 3;
  const float* src = (m == 0 ? wg : (m == 1 ? wu : wd)) + (size_t)(ge + j) * WEL;
  unsigned short* dst = wbuf + (size_t)(j * 3 + m) * WEL;
  const int k0 = blockIdx.x * 64, n0 = blockIdx.y * 64;
  const int tid = threadIdx.x;
#pragma unroll
  for (int u = 0; u < 4; ++u) {
    int idx = tid + u * 256;
    int kr = idx >> 4;
    int nc = (idx & 15) * 4;
    f32x4 v = *(const f32x4*)(src + (size_t)(k0 + kr) * 2880 + (n0 + nc));
#pragma unroll
    for (int q = 0; q < 4; ++q) st[nc + q][kr] = f2bf(v[q]);
  }
  __syncthreads();
  int n = tid >> 2;
  int kc = (tid & 3) * 16;
  u16x8 a = *(const u16x8*)(&st[n][kc]);
  u16x8 b = *(const u16x8*)(&st[n][kc + 8]);
  unsigned short* po = dst + (size_t)(n0 + n) * 2880 + (k0 + kc);
  *(u16x8*)(po) = a;
  *(u16x8*)(po + 8) = b;
}

// ---------------- router: 4 tokens/wave (no spill), butterfly reduce ----------------
__global__ __launch_bounds__(256) void router_kernel(const float* __restrict__ x,
                                                     const float* __restrict__ rw,
                                                     const float* __restrict__ rb,
                                                     float* __restrict__ aff,
                                                     int* __restrict__ cnt,
                                                     int* __restrict__ lst) {
  const int wv = threadIdx.x >> 6, lane = threadIdx.x & 63;
  const int tok0 = (blockIdx.x * 4 + wv) * 4;
  float acc[4][NEXP];
#pragma unroll
  for (int t = 0; t < 4; ++t)
#pragma unroll
    for (int e = 0; e < NEXP; ++e) acc[t][e] = 0.f;

#pragma unroll
  for (int it = 0; it < 12; ++it) {
    int c = it * 64 + lane;               // 16B chunk id, 720 per row
    if (c < 720) {
      f32x4 w4[NEXP];
#pragma unroll
      for (int e = 0; e < NEXP; ++e)
        w4[e] = *(const f32x4*)(rw + (size_t)e * HDIM + c * 4);
#pragma unroll
      for (int t = 0; t < 4; ++t) {
        f32x4 xv = *(const f32x4*)(x + (size_t)(tok0 + t) * HDIM + c * 4);
#pragma unroll
        for (int e = 0; e < NEXP; ++e)
          acc[t][e] += xv[0] * w4[e][0] + xv[1] * w4[e][1] + xv[2] * w4[e][2] + xv[3] * w4[e][3];
      }
    }
  }
#pragma unroll
  for (int t = 0; t < 4; ++t)
#pragma unroll
    for (int e = 0; e < NEXP; ++e) {
#pragma unroll
      for (int m = 32; m; m >>= 1) acc[t][e] += __shfl_xor(acc[t][e], m);
    }
  if (lane < 4) {
    int tok = tok0 + lane;
    float lg[NEXP];
#pragma unroll
    for (int e = 0; e < NEXP; ++e) lg[e] = acc[lane][e] + rb[e];
    bool used[NEXP];
#pragma unroll
    for (int e = 0; e < NEXP; ++e) used[e] = false;
    int bi[TOPK]; float bv[TOPK];
#pragma unroll
    for (int s = 0; s < TOPK; ++s) {
      int best = 0; float vbest = -1e30f;
#pragma unroll
      for (int e = 0; e < NEXP; ++e)
        if (!used[e] && lg[e] > vbest) { vbest = lg[e]; best = e; }
      used[best] = true; bi[s] = best; bv[s] = vbest;
    }
    float mx = bv[0];
    float w[TOPK]; float ssum = 0.f;
#pragma unroll
    for (int s = 0; s < TOPK; ++s) { w[s] = __expf(bv[s] - mx); ssum += w[s]; }
    float o[NEXP];
#pragma unroll
    for (int e = 0; e < NEXP; ++e) o[e] = 0.f;
#pragma unroll
    for (int s = 0; s < TOPK; ++s) o[bi[s]] = w[s] / ssum;
#pragma unroll
    for (int e = 0; e < NEXP; ++e) aff[(size_t)tok * NEXP + e] = o[e];
#pragma unroll
    for (int s = 0; s < TOPK; ++s) {
      int p = atomicAdd(&cnt[bi[s]], 1);
      lst[bi[s] * T_TOK + p] = tok;
    }
  }
}

// ---------------- sched: per-expert block/slot prefix offsets (group-local) ----------------
__global__ void sched_kernel(const int* __restrict__ cnt, int* __restrict__ ebs,
                             int* __restrict__ ess, int* __restrict__ gtot, int G) {
  if (threadIdx.x == 0 && blockIdx.x == 0) {
    int ng = NEXP / G;
    for (int g = 0; g < ng; ++g) {
      int b = 0, s = 0;
      for (int j = 0; j < G; ++j) {
        int e = g * G + j;
        ebs[e] = b; ess[e] = s;
        b += (cnt[e] + BM - 1) / BM;
        s += cnt[e];
      }
      gtot[g] = b;
    }
  }
}

// ---------------- gate/up fused GEMM + SwiGLU + affinity -> h4 (per-slot rows) ----------
__global__ __launch_bounds__(256) void gateup_kernel(
    const unsigned short* __restrict__ xb, const unsigned short* __restrict__ wbuf,
    const float* __restrict__ aff, const int* __restrict__ lst,
    const int* __restrict__ cnts, const int* __restrict__ ebs,
    const int* __restrict__ ess, const int* __restrict__ gtot_g,
    unsigned short* __restrict__ h4, int ge, int G) {
  const int bx = blockIdx.x;
  if (bx >= *gtot_g) return;
  int j = 0;
  for (int t = 1; t < G; ++t) j += (bx >= ebs[ge + t]) ? 1 : 0;
  const int e = ge + j;
  const int cnt = cnts[e];
  const int m0 = (bx - ebs[e]) * BM;
  const int slotbase = ess[e];
  const unsigned short* wgt = wbuf + (size_t)j * 3 * WEL;
  const unsigned short* wut = wgt + WEL;

  __shared__ __align__(16) unsigned short Al[BM * BK];     // 16KB
  __shared__ __align__(16) unsigned short Bgl[BN * BK];    // 12KB
  __shared__ __align__(16) unsigned short Bul[BN * BK];    // 12KB

  const int tid = threadIdx.x;
  const int n0 = blockIdx.y * BN;
  const int wv = tid >> 6, lane = tid & 63;
  const int msub = (wv >> 1) * 64, nsub = (wv & 1) * 48;
  const int l15 = lane & 15, l4 = lane >> 4;
  const int lr = lane >> 3, lc = lane & 7;
  const int* mylst = lst + e * T_TOK;

  const unsigned short* asrc[4]; unsigned short* adst[4];
#pragma unroll
  for (int u = 0; u < 4; ++u) {
    int s = u * 4 + wv;
    int r = s * 8 + lr;
    int tok = mylst[min(m0 + r, cnt - 1)];
    asrc[u] = xb + (size_t)tok * HDIM + (lc ^ (r & 7)) * 8;
    adst[u] = &Al[s * 512];
  }
  const unsigned short* bgsrc[3]; const unsigned short* busrc[3];
  unsigned short* bgdst[3]; unsigned short* budst[3];
#pragma unroll
  for (int u = 0; u < 3; ++u) {
    int s = u * 4 + wv;
    int r = s * 8 + lr;
    size_t off = (size_t)(n0 + r) * HDIM + (size_t)((lc ^ (r & 7)) * 8);
    bgsrc[u] = wgt + off; busrc[u] = wut + off;
    bgdst[u] = &Bgl[s * 512]; budst[u] = &Bul[s * 512];
  }

  f32x4 accg[4][3]; f32x4 accu[4][3];
#pragma unroll
  for (int mf = 0; mf < 4; ++mf)
#pragma unroll
    for (int nf = 0; nf < 3; ++nf) { accg[mf][nf] = (f32x4)0.f; accu[mf][nf] = (f32x4)0.f; }

#pragma unroll 1
  for (int k0 = 0; k0 < HDIM; k0 += BK) {
#pragma unroll
    for (int u = 0; u < 4; ++u) gload16(asrc[u] + k0, adst[u]);
#pragma unroll
    for (int u = 0; u < 3; ++u) {
      gload16(bgsrc[u] + k0, bgdst[u]);
      gload16(busrc[u] + k0, budst[u]);
    }
    __syncthreads();
#pragma unroll
    for (int kk = 0; kk < 2; ++kk) {
      s16x8 af[4];
#pragma unroll
      for (int mf = 0; mf < 4; ++mf) {
        int R = msub + mf * 16 + l15;
        int sl = (kk * 4 + l4) ^ (R & 7);
        af[mf] = *(const s16x8*)(&Al[R * 64 + sl * 8]);
      }
#pragma unroll
      for (int nf = 0; nf < 3; ++nf) {
        int R = nsub + nf * 16 + l15;
        int sl = (kk * 4 + l4) ^ (R & 7);
        s16x8 bg = *(const s16x8*)(&Bgl[R * 64 + sl * 8]);
        s16x8 bu = *(const s16x8*)(&Bul[R * 64 + sl * 8]);
#pragma unroll
        for (int mf = 0; mf < 4; ++mf) {
          accg[mf][nf] = __builtin_amdgcn_mfma_f32_16x16x32_bf16(af[mf], bg, accg[mf][nf], 0, 0, 0);
          accu[mf][nf] = __builtin_amdgcn_mfma_f32_16x16x32_bf16(af[mf], bu, accu[mf][nf], 0, 0, 0);
        }
      }
    }
    __syncthreads();
  }

#pragma unroll
  for (int mf = 0; mf < 4; ++mf)
#pragma unroll
    for (int r = 0; r < 4; ++r) {
      int slot = m0 + msub + mf * 16 + l4 * 4 + r;
      if (slot < cnt) {
        int tok = mylst[slot];
        float av = aff[(size_t)tok * NEXP + e];
#pragma unroll
        for (int nf = 0; nf < 3; ++nf) {
          float g = accg[mf][nf][r], uu = accu[mf][nf][r];
          float hv = (g / (1.f + __expf(-g))) * uu * av;
          int col = n0 + nsub + nf * 16 + l15;
          h4[(size_t)(slotbase + slot) * IDIM + col] = f2bf(hv);
        }
      }
    }
}

// ---------------- down GEMM: out[tok] += h4[slot] @ WdT (atomic combine) ----------------
__global__ __launch_bounds__(256) void down_kernel(
    const unsigned short* __restrict__ h4, const unsigned short* __restrict__ wbuf,
    float* __restrict__ out, const int* __restrict__ lst,
    const int* __restrict__ cnts, const int* __restrict__ ebs,
    const int* __restrict__ ess, const int* __restrict__ gtot_g,
    int ge, int G) {
  const int bx = blockIdx.x;
  if (bx >= *gtot_g) return;
  int j = 0;
  for (int t = 1; t < G; ++t) j += (bx >= ebs[ge + t]) ? 1 : 0;
  const int e = ge + j;
  const int cnt = cnts[e];
  const int m0 = (bx - ebs[e]) * BM;
  const int slotbase = ess[e];
  const unsigned short* wdt = wbuf + (size_t)j * 3 * WEL + 2 * (size_t)WEL;

  __shared__ __align__(16) unsigned short Al[BM * BK];   // 16KB
  __shared__ __align__(16) unsigned short Bl[BN * BK];   // 12KB

  const int tid = threadIdx.x;
  const int n0 = blockIdx.y * BN;
  const int wv = tid >> 6, lane = tid & 63;
  const int msub = (wv >> 1) * 64, nsub = (wv & 1) * 48;
  const int l15 = lane & 15, l4 = lane >> 4;
  const int lr = lane >> 3, lc = lane & 7;
  const int* mylst = lst + e * T_TOK;

  const unsigned short* asrc[4]; unsigned short* adst[4];
#pragma unroll
  for (int u = 0; u < 4; ++u) {
    int s = u * 4 + wv;
    int r = s * 8 + lr;
    int hr = min(m0 + r, cnt - 1);                 // contiguous h4 rows, clamped
    asrc[u] = h4 + (size_t)(slotbase + hr) * IDIM + (lc ^ (r & 7)) * 8;
    adst[u] = &Al[s * 512];
  }
  const unsigned short* bsrc[3]; unsigned short* bdst[3];
#pragma unroll
  for (int u = 0; u < 3; ++u) {
    int s = u * 4 + wv;
    int r = s * 8 + lr;
    bsrc[u] = wdt + (size_t)(n0 + r) * IDIM + (size_t)((lc ^ (r & 7)) * 8);
    bdst[u] = &Bl[s * 512];
  }

  f32x4 acc[4][3];
#pragma unroll
  for (int mf = 0; mf < 4; ++mf)
#pragma unroll
    for (int nf = 0; nf < 3; ++nf) acc[mf][nf] = (f32x4)0.f;

#pragma unroll 1
  for (int k0 = 0; k0 < IDIM; k0 += BK) {
#pragma unroll
    for (int u = 0; u < 4; ++u) gload16(asrc[u] + k0, adst[u]);
#pragma unroll
    for (int u = 0; u < 3; ++u) gload16(bsrc[u] + k0, bdst[u]);
    __syncthreads();
#pragma unroll
    for (int kk = 0; kk < 2; ++kk) {
      s16x8 af[4];
#pragma unroll
      for (int mf = 0; mf < 4; ++mf) {
        int R = msub + mf * 16 + l15;
        int sl = (kk * 4 + l4) ^ (R & 7);
        af[mf] = *(const s16x8*)(&Al[R * 64 + sl * 8]);
      }
#pragma unroll
      for (int nf = 0; nf < 3; ++nf) {
        int R = nsub + nf * 16 + l15;
        int sl = (kk * 4 + l4) ^ (R & 7);
        s16x8 bb = *(const s16x8*)(&Bl[R * 64 + sl * 8]);
#pragma unroll
        for (int mf = 0; mf < 4; ++mf)
          acc[mf][nf] = __builtin_amdgcn_mfma_f32_16x16x32_bf16(af[mf], bb, acc[mf][nf], 0, 0, 0);
      }
    }
    __syncthreads();
  }

#pragma unroll
  for (int mf = 0; mf < 4; ++mf)
#pragma unroll
    for (int r = 0; r < 4; ++r) {
      int slot = m0 + msub + mf * 16 + l4 * 4 + r;
      if (slot < cnt) {
        int tok = mylst[slot];
#pragma unroll
        for (int nf = 0; nf < 3; ++nf) {
          int col = n0 + nsub + nf * 16 + l15;
          atomicAdd(out + (size_t)tok * HDIM + col, acc[mf][nf][r]);
        }
      }
    }
}

// ---------------- launcher ----------------
extern "C" void kernel_launch(void* const* d_in, const int* in_sizes, int n_in,
                              void* d_out, int out_size, void* d_ws, size_t ws_size,
                              hipStream_t stream) {
  (void)in_sizes; (void)n_in;
  const float* x  = (const float*)d_in[0];
  const float* rw = (const float*)d_in[1];
  const float* rb = (const float*)d_in[2];
  const float* wg = (const float*)d_in[3];
  const float* wu = (const float*)d_in[4];
  const float* wd = (const float*)d_in[5];
  float* out = (float*)d_out;

  // fixed-offset small buffers
  char* ws = (char*)d_ws;
  float* aff = (float*)ws;                         // 131072 B
  int*   cnt = (int*)(ws + 131072);                // 512 B
  int*   lst = (int*)(ws + 131584);                // 131072 B
  int*   ebs = (int*)(ws + 262656);                // 64 B
  int*   ess = (int*)(ws + 262720);                // 64 B
  int*   gtot = (int*)(ws + 262784);               // 64 B (+pad)
  unsigned short* xb = (unsigned short*)(ws + 263168);   // 23,592,960 B
  const size_t OFF_H4 = 263168 + 23592960ull;            // = 23,856,128

  // choose expert-group size G by workspace capacity
  const size_t WELB = (size_t)WEL * 2;             // 16,588,800 B per bf16 matrix
  int G = 1;
  {
    size_t need8 = OFF_H4 + (size_t)16384 * IDIM * 2 + 8 * 3 * WELB;  // ~516 MB
    size_t need2 = OFF_H4 + (size_t)8192  * IDIM * 2 + 2 * 3 * WELB;  // ~171 MB
    if (ws_size >= need8) G = 8;
    else if (ws_size >= need2) G = 2;
  }
  const size_t h4b = (size_t)((G == 8) ? 16384 : (G == 2 ? 8192 : 4096)) * IDIM * 2;
  unsigned short* h4   = (unsigned short*)(ws + OFF_H4);
  unsigned short* wbuf = (unsigned short*)(ws + OFF_H4 + h4b);

  const int NG = NEXP / G;
  const int GUX = (G == 8) ? 136 : (G == 2 ? 66 : 33);  // worst-case m-blocks per group

  hipMemsetAsync(out, 0, (size_t)out_size * sizeof(float), stream);
  hipMemsetAsync(cnt, 0, 512, stream);
  cvt_kernel<<<(T_TOK * HDIM / 8) / 256, 256, 0, stream>>>(x, xb);
  router_kernel<<<T_TOK / 16, 256, 0, stream>>>(x, rw, rb, aff, cnt, lst);
  sched_kernel<<<1, 64, 0, stream>>>(cnt, ebs, ess, gtot, G);

  for (int g = 0; g < NG; ++g) {
    int ge = g * G;
    transpose_group_kernel<<<dim3(45, 45, 3 * G), 256, 0, stream>>>(wg, wu, wd, wbuf, ge);
    gateup_kernel<<<dim3(GUX, IDIM / BN), 256, 0, stream>>>(
        xb, wbuf, aff, lst, cnt, ebs, ess, gtot + g, h4, ge, G);
    down_kernel<<<dim3(GUX, HDIM / BN), 256, 0, stream>>>(
        h4, wbuf, out, lst, cnt, ebs, ess, gtot + g, ge, G);
  }
}

// Round 6
// 1409.644 us; speedup vs baseline: 2.7221x; 1.0377x over previous
//
#include <hip/hip_runtime.h>

// ---------------- problem constants ----------------
#define T_TOK 4096      // B*S tokens
#define HDIM  2880
#define IDIM  2880
#define NEXP  8
#define TOPK  4
#define WEL   (2880 * 2880)   // elems per weight matrix

// GEMM tiling: 128x96 block tile, BK=64, 4 waves (2x2) of 64x48.
// LDS tiles LINEAR [row][64] bf16 (128B rows), XOR-swizzled on the 16B k-slot:
//   physical_slot = logical_slot ^ (row & 7)
// global_load_lds writes lane l -> base + l*16 (linear); per-lane GLOBAL source
// is pre-swizzled so swizzled reads see logical order (both-sides involution).
// Double-buffered with raw s_barrier + counted vmcnt (T3/T4 minimum):
//   stage(next); s_waitcnt vmcnt(NL); s_barrier; compute(cur); s_barrier
#define BM 128
#define BN 96
#define BK 64
#define NPAN 30         // 2880 / 96 output n-panels
#define ASZ (BM * BK)   // 8192 elems / 16 KB per buffer half
#define BSZ (BN * BK)   // 6144 elems / 12 KB per buffer half
#define NSTEP 45        // 2880 / 64 (NSTEP-1 = 44, even -> clean 2x unroll)

typedef __attribute__((ext_vector_type(8))) short  s16x8;
typedef __attribute__((ext_vector_type(8))) unsigned short u16x8;
typedef __attribute__((ext_vector_type(4))) float  f32x4;

__device__ __forceinline__ unsigned short f2bf(float f) {
  unsigned int u = __float_as_uint(f);
  u += 0x7FFFu + ((u >> 16) & 1u);
  return (unsigned short)(u >> 16);
}

__device__ __forceinline__ void gload16(const unsigned short* g, unsigned short* l) {
  __builtin_amdgcn_global_load_lds(
      (const __attribute__((address_space(1))) void*)g,
      (__attribute__((address_space(3))) void*)l, 16, 0, 0);
}

// ---------------- x f32 -> bf16 ----------------
__global__ __launch_bounds__(256) void cvt_kernel(const float* __restrict__ x,
                                                  unsigned short* __restrict__ xb) {
  int i = blockIdx.x * 256 + threadIdx.x;
  const f32x4* p = (const f32x4*)x;
  f32x4 a = p[2 * (size_t)i];
  f32x4 b = p[2 * (size_t)i + 1];
  u16x8 o;
  o[0] = f2bf(a[0]); o[1] = f2bf(a[1]); o[2] = f2bf(a[2]); o[3] = f2bf(a[3]);
  o[4] = f2bf(b[0]); o[5] = f2bf(b[1]); o[6] = f2bf(b[2]); o[7] = f2bf(b[3]);
  *(u16x8*)(xb + (size_t)i * 8) = o;
}

// ---------------- weight transpose+convert for a group of G experts ----------------
__global__ __launch_bounds__(256) void transpose_group_kernel(
    const float* __restrict__ wg, const float* __restrict__ wu,
    const float* __restrict__ wd, unsigned short* __restrict__ wbuf, int ge) {
  __shared__ unsigned short st[64][72];
  const int z = blockIdx.z, j = z / 3, m = z % 3;
  const float* src = (m == 0 ? wg : (m == 1 ? wu : wd)) + (size_t)(ge + j) * WEL;
  unsigned short* dst = wbuf + (size_t)(j * 3 + m) * WEL;
  const int k0 = blockIdx.x * 64, n0 = blockIdx.y * 64;
  const int tid = threadIdx.x;
#pragma unroll
  for (int u = 0; u < 4; ++u) {
    int idx = tid + u * 256;
    int kr = idx >> 4;
    int nc = (idx & 15) * 4;
    f32x4 v = *(const f32x4*)(src + (size_t)(k0 + kr) * 2880 + (n0 + nc));
#pragma unroll
    for (int q = 0; q < 4; ++q) st[nc + q][kr] = f2bf(v[q]);
  }
  __syncthreads();
  int n = tid >> 2;
  int kc = (tid & 3) * 16;
  u16x8 a = *(const u16x8*)(&st[n][kc]);
  u16x8 b = *(const u16x8*)(&st[n][kc + 8]);
  unsigned short* po = dst + (size_t)(n0 + n) * 2880 + (k0 + kc);
  *(u16x8*)(po) = a;
  *(u16x8*)(po + 8) = b;
}

// ---------------- router: 4 tokens/wave, butterfly reduce ----------------
__global__ __launch_bounds__(256) void router_kernel(const float* __restrict__ x,
                                                     const float* __restrict__ rw,
                                                     const float* __restrict__ rb,
                                                     float* __restrict__ aff,
                                                     int* __restrict__ cnt,
                                                     int* __restrict__ lst) {
  const int wv = threadIdx.x >> 6, lane = threadIdx.x & 63;
  const int tok0 = (blockIdx.x * 4 + wv) * 4;
  float acc[4][NEXP];
#pragma unroll
  for (int t = 0; t < 4; ++t)
#pragma unroll
    for (int e = 0; e < NEXP; ++e) acc[t][e] = 0.f;

#pragma unroll
  for (int it = 0; it < 12; ++it) {
    int c = it * 64 + lane;
    if (c < 720) {
      f32x4 w4[NEXP];
#pragma unroll
      for (int e = 0; e < NEXP; ++e)
        w4[e] = *(const f32x4*)(rw + (size_t)e * HDIM + c * 4);
#pragma unroll
      for (int t = 0; t < 4; ++t) {
        f32x4 xv = *(const f32x4*)(x + (size_t)(tok0 + t) * HDIM + c * 4);
#pragma unroll
        for (int e = 0; e < NEXP; ++e)
          acc[t][e] += xv[0] * w4[e][0] + xv[1] * w4[e][1] + xv[2] * w4[e][2] + xv[3] * w4[e][3];
      }
    }
  }
#pragma unroll
  for (int t = 0; t < 4; ++t)
#pragma unroll
    for (int e = 0; e < NEXP; ++e) {
#pragma unroll
      for (int m = 32; m; m >>= 1) acc[t][e] += __shfl_xor(acc[t][e], m);
    }
  if (lane < 4) {
    int tok = tok0 + lane;
    float lg[NEXP];
#pragma unroll
    for (int e = 0; e < NEXP; ++e) lg[e] = acc[lane][e] + rb[e];
    bool used[NEXP];
#pragma unroll
    for (int e = 0; e < NEXP; ++e) used[e] = false;
    int bi[TOPK]; float bv[TOPK];
#pragma unroll
    for (int s = 0; s < TOPK; ++s) {
      int best = 0; float vbest = -1e30f;
#pragma unroll
      for (int e = 0; e < NEXP; ++e)
        if (!used[e] && lg[e] > vbest) { vbest = lg[e]; best = e; }
      used[best] = true; bi[s] = best; bv[s] = vbest;
    }
    float mx = bv[0];
    float w[TOPK]; float ssum = 0.f;
#pragma unroll
    for (int s = 0; s < TOPK; ++s) { w[s] = __expf(bv[s] - mx); ssum += w[s]; }
    float o[NEXP];
#pragma unroll
    for (int e = 0; e < NEXP; ++e) o[e] = 0.f;
#pragma unroll
    for (int s = 0; s < TOPK; ++s) o[bi[s]] = w[s] / ssum;
#pragma unroll
    for (int e = 0; e < NEXP; ++e) aff[(size_t)tok * NEXP + e] = o[e];
#pragma unroll
    for (int s = 0; s < TOPK; ++s) {
      int p = atomicAdd(&cnt[bi[s]], 1);
      lst[bi[s] * T_TOK + p] = tok;
    }
  }
}

// ---------------- sched: per-expert BLOCK prefixes (incl. n-panels) + slot prefixes ----------------
// gbs[e] = group-local exclusive prefix of ceil(cnt_e/BM)*NPAN ; ess[e] = slot prefix ; gtot[g] = group total
__global__ void sched_kernel(const int* __restrict__ cnt, int* __restrict__ gbs,
                             int* __restrict__ ess, int* __restrict__ gtot, int G) {
  if (threadIdx.x == 0 && blockIdx.x == 0) {
    int ng = NEXP / G;
    for (int g = 0; g < ng; ++g) {
      int b = 0, s = 0;
      for (int j = 0; j < G; ++j) {
        int e = g * G + j;
        gbs[e] = b; ess[e] = s;
        b += ((cnt[e] + BM - 1) / BM) * NPAN;
        s += cnt[e];
      }
      gtot[g] = b;
    }
  }
}

// locate (expert, m0, n0) from 1D block id; expert-major, n-outer, m-inner
__device__ __forceinline__ bool locate(int bx, const int* gbs, const int* cnts,
                                       int ge, int G, const int* gtot_g,
                                       int& e, int& m0, int& n0, int& cnt) {
  if (bx >= *gtot_g) return false;
  int j = 0;
  for (int t = 1; t < G; ++t) j += (bx >= gbs[ge + t]) ? 1 : 0;
  e = ge + j;
  cnt = cnts[e];
  int mb = (cnt + BM - 1) >> 7;
  int local = bx - gbs[e];
  int nIdx = local / mb;
  int mIdx = local - nIdx * mb;
  m0 = mIdx * BM;
  n0 = nIdx * BN;
  return true;
}

// ---------------- gate/up fused GEMM + SwiGLU + affinity -> h4 (per-slot rows) ----------
__global__ __launch_bounds__(256) void gateup_kernel(
    const unsigned short* __restrict__ xb, const unsigned short* __restrict__ wbuf,
    const float* __restrict__ aff, const int* __restrict__ lst,
    const int* __restrict__ cnts, const int* __restrict__ gbs,
    const int* __restrict__ ess, const int* __restrict__ gtot_g,
    unsigned short* __restrict__ h4, int ge, int G) {
  int e, m0, n0, cnt;
  if (!locate(blockIdx.x, gbs, cnts, ge, G, gtot_g, e, m0, n0, cnt)) return;
  const int j = e - ge;
  const int slotbase = ess[e];
  const unsigned short* wgt = wbuf + (size_t)j * 3 * WEL;
  const unsigned short* wut = wgt + WEL;

  __shared__ __align__(16) unsigned short Al[2 * ASZ];    // 32KB dbuf
  __shared__ __align__(16) unsigned short Bgl[2 * BSZ];   // 24KB
  __shared__ __align__(16) unsigned short Bul[2 * BSZ];   // 24KB

  const int tid = threadIdx.x;
  const int wv = tid >> 6, lane = tid & 63;
  const int msub = (wv >> 1) * 64, nsub = (wv & 1) * 48;
  const int l15 = lane & 15, l4 = lane >> 4;
  const int lr = lane >> 3, lc = lane & 7;
  const int* mylst = lst + e * T_TOK;

  const unsigned short* asrc[4]; unsigned short* adst[4];
#pragma unroll
  for (int u = 0; u < 4; ++u) {
    int s = u * 4 + wv;
    int r = s * 8 + lr;
    int tok = mylst[min(m0 + r, cnt - 1)];
    asrc[u] = xb + (size_t)tok * HDIM + (lc ^ (r & 7)) * 8;
    adst[u] = &Al[s * 512];
  }
  const unsigned short* bgsrc[3]; const unsigned short* busrc[3];
  unsigned short* bgdst[3]; unsigned short* budst[3];
#pragma unroll
  for (int u = 0; u < 3; ++u) {
    int s = u * 4 + wv;
    int r = s * 8 + lr;
    size_t off = (size_t)(n0 + r) * HDIM + (size_t)((lc ^ (r & 7)) * 8);
    bgsrc[u] = wgt + off; busrc[u] = wut + off;
    bgdst[u] = &Bgl[s * 512]; budst[u] = &Bul[s * 512];
  }

  f32x4 accg[4][3]; f32x4 accu[4][3];
#pragma unroll
  for (int mf = 0; mf < 4; ++mf)
#pragma unroll
    for (int nf = 0; nf < 3; ++nf) { accg[mf][nf] = (f32x4)0.f; accu[mf][nf] = (f32x4)0.f; }

  auto stage = [&](int buf, int k0) {   // 10 VMEM ops per wave
    int ao = buf * ASZ, bo = buf * BSZ;
#pragma unroll
    for (int u = 0; u < 4; ++u) gload16(asrc[u] + k0, adst[u] + ao);
#pragma unroll
    for (int u = 0; u < 3; ++u) {
      gload16(bgsrc[u] + k0, bgdst[u] + bo);
      gload16(busrc[u] + k0, budst[u] + bo);
    }
  };
  auto compute = [&](int buf) {
    const unsigned short* Ab = Al + buf * ASZ;
    const unsigned short* Bg = Bgl + buf * BSZ;
    const unsigned short* Bu = Bul + buf * BSZ;
#pragma unroll
    for (int kk = 0; kk < 2; ++kk) {
      s16x8 af[4];
#pragma unroll
      for (int mf = 0; mf < 4; ++mf) {
        int R = msub + mf * 16 + l15;
        int sl = (kk * 4 + l4) ^ (R & 7);
        af[mf] = *(const s16x8*)(&Ab[R * 64 + sl * 8]);
      }
#pragma unroll
      for (int nf = 0; nf < 3; ++nf) {
        int R = nsub + nf * 16 + l15;
        int sl = (kk * 4 + l4) ^ (R & 7);
        s16x8 bg = *(const s16x8*)(&Bg[R * 64 + sl * 8]);
        s16x8 bu = *(const s16x8*)(&Bu[R * 64 + sl * 8]);
#pragma unroll
        for (int mf = 0; mf < 4; ++mf) {
          accg[mf][nf] = __builtin_amdgcn_mfma_f32_16x16x32_bf16(af[mf], bg, accg[mf][nf], 0, 0, 0);
          accu[mf][nf] = __builtin_amdgcn_mfma_f32_16x16x32_bf16(af[mf], bu, accu[mf][nf], 0, 0, 0);
        }
      }
    }
  };

  // counted-vmcnt double-buffered pipeline (vmcnt(10) = this wave's prev-tile loads done)
  stage(0, 0);
#pragma unroll 1
  for (int t = 0; t < NSTEP - 1; t += 2) {
    stage(1, (t + 1) * BK);
    asm volatile("s_waitcnt vmcnt(10)" ::: "memory");
    __builtin_amdgcn_s_barrier();
    compute(0);
    __builtin_amdgcn_s_barrier();
    stage(0, (t + 2) * BK);
    asm volatile("s_waitcnt vmcnt(10)" ::: "memory");
    __builtin_amdgcn_s_barrier();
    compute(1);
    __builtin_amdgcn_s_barrier();
  }
  asm volatile("s_waitcnt vmcnt(0)" ::: "memory");
  __builtin_amdgcn_s_barrier();
  compute(0);   // tile 44 lives in buf 0

#pragma unroll
  for (int mf = 0; mf < 4; ++mf)
#pragma unroll
    for (int r = 0; r < 4; ++r) {
      int slot = m0 + msub + mf * 16 + l4 * 4 + r;
      if (slot < cnt) {
        int tok = mylst[slot];
        float av = aff[(size_t)tok * NEXP + e];
#pragma unroll
        for (int nf = 0; nf < 3; ++nf) {
          float g = accg[mf][nf][r], uu = accu[mf][nf][r];
          float hv = (g / (1.f + __expf(-g))) * uu * av;
          int col = n0 + nsub + nf * 16 + l15;
          h4[(size_t)(slotbase + slot) * IDIM + col] = f2bf(hv);
        }
      }
    }
}

// ---------------- down GEMM: out[tok] += h4[slot] @ WdT (atomic combine) ----------------
__global__ __launch_bounds__(256) void down_kernel(
    const unsigned short* __restrict__ h4, const unsigned short* __restrict__ wbuf,
    float* __restrict__ out, const int* __restrict__ lst,
    const int* __restrict__ cnts, const int* __restrict__ gbs,
    const int* __restrict__ ess, const int* __restrict__ gtot_g,
    int ge, int G) {
  int e, m0, n0, cnt;
  if (!locate(blockIdx.x, gbs, cnts, ge, G, gtot_g, e, m0, n0, cnt)) return;
  const int j = e - ge;
  const int slotbase = ess[e];
  const unsigned short* wdt = wbuf + (size_t)j * 3 * WEL + 2 * (size_t)WEL;

  __shared__ __align__(16) unsigned short Al[2 * ASZ];   // 32KB
  __shared__ __align__(16) unsigned short Bl[2 * BSZ];   // 24KB

  const int tid = threadIdx.x;
  const int wv = tid >> 6, lane = tid & 63;
  const int msub = (wv >> 1) * 64, nsub = (wv & 1) * 48;
  const int l15 = lane & 15, l4 = lane >> 4;
  const int lr = lane >> 3, lc = lane & 7;
  const int* mylst = lst + e * T_TOK;

  const unsigned short* asrc[4]; unsigned short* adst[4];
#pragma unroll
  for (int u = 0; u < 4; ++u) {
    int s = u * 4 + wv;
    int r = s * 8 + lr;
    int hr = min(m0 + r, cnt - 1);
    asrc[u] = h4 + (size_t)(slotbase + hr) * IDIM + (lc ^ (r & 7)) * 8;
    adst[u] = &Al[s * 512];
  }
  const unsigned short* bsrc[3]; unsigned short* bdst[3];
#pragma unroll
  for (int u = 0; u < 3; ++u) {
    int s = u * 4 + wv;
    int r = s * 8 + lr;
    bsrc[u] = wdt + (size_t)(n0 + r) * IDIM + (size_t)((lc ^ (r & 7)) * 8);
    bdst[u] = &Bl[s * 512];
  }

  f32x4 acc[4][3];
#pragma unroll
  for (int mf = 0; mf < 4; ++mf)
#pragma unroll
    for (int nf = 0; nf < 3; ++nf) acc[mf][nf] = (f32x4)0.f;

  auto stage = [&](int buf, int k0) {   // 7 VMEM ops per wave
    int ao = buf * ASZ, bo = buf * BSZ;
#pragma unroll
    for (int u = 0; u < 4; ++u) gload16(asrc[u] + k0, adst[u] + ao);
#pragma unroll
    for (int u = 0; u < 3; ++u) gload16(bsrc[u] + k0, bdst[u] + bo);
  };
  auto compute = [&](int buf) {
    const unsigned short* Ab = Al + buf * ASZ;
    const unsigned short* Bb = Bl + buf * BSZ;
#pragma unroll
    for (int kk = 0; kk < 2; ++kk) {
      s16x8 af[4];
#pragma unroll
      for (int mf = 0; mf < 4; ++mf) {
        int R = msub + mf * 16 + l15;
        int sl = (kk * 4 + l4) ^ (R & 7);
        af[mf] = *(const s16x8*)(&Ab[R * 64 + sl * 8]);
      }
#pragma unroll
      for (int nf = 0; nf < 3; ++nf) {
        int R = nsub + nf * 16 + l15;
        int sl = (kk * 4 + l4) ^ (R & 7);
        s16x8 bb = *(const s16x8*)(&Bb[R * 64 + sl * 8]);
#pragma unroll
        for (int mf = 0; mf < 4; ++mf)
          acc[mf][nf] = __builtin_amdgcn_mfma_f32_16x16x32_bf16(af[mf], bb, acc[mf][nf], 0, 0, 0);
      }
    }
  };

  stage(0, 0);
#pragma unroll 1
  for (int t = 0; t < NSTEP - 1; t += 2) {
    stage(1, (t + 1) * BK);
    asm volatile("s_waitcnt vmcnt(7)" ::: "memory");
    __builtin_amdgcn_s_barrier();
    compute(0);
    __builtin_amdgcn_s_barrier();
    stage(0, (t + 2) * BK);
    asm volatile("s_waitcnt vmcnt(7)" ::: "memory");
    __builtin_amdgcn_s_barrier();
    compute(1);
    __builtin_amdgcn_s_barrier();
  }
  asm volatile("s_waitcnt vmcnt(0)" ::: "memory");
  __builtin_amdgcn_s_barrier();
  compute(0);

#pragma unroll
  for (int mf = 0; mf < 4; ++mf)
#pragma unroll
    for (int r = 0; r < 4; ++r) {
      int slot = m0 + msub + mf * 16 + l4 * 4 + r;
      if (slot < cnt) {
        int tok = mylst[slot];
#pragma unroll
        for (int nf = 0; nf < 3; ++nf) {
          int col = n0 + nsub + nf * 16 + l15;
          atomicAdd(out + (size_t)tok * HDIM + col, acc[mf][nf][r]);
        }
      }
    }
}

// ---------------- launcher ----------------
extern "C" void kernel_launch(void* const* d_in, const int* in_sizes, int n_in,
                              void* d_out, int out_size, void* d_ws, size_t ws_size,
                              hipStream_t stream) {
  (void)in_sizes; (void)n_in;
  const float* x  = (const float*)d_in[0];
  const float* rw = (const float*)d_in[1];
  const float* rb = (const float*)d_in[2];
  const float* wg = (const float*)d_in[3];
  const float* wu = (const float*)d_in[4];
  const float* wd = (const float*)d_in[5];
  float* out = (float*)d_out;

  // fixed-offset small buffers
  char* ws = (char*)d_ws;
  float* aff = (float*)ws;                         // 131072 B
  int*   cnt = (int*)(ws + 131072);                // 512 B
  int*   lst = (int*)(ws + 131584);                // 131072 B
  int*   gbs = (int*)(ws + 262656);                // 64 B
  int*   ess = (int*)(ws + 262720);                // 64 B
  int*   gtot = (int*)(ws + 262784);               // 64 B (+pad)
  unsigned short* xb = (unsigned short*)(ws + 263168);   // 23,592,960 B
  const size_t OFF_H4 = 263168 + 23592960ull;

  const size_t WELB = (size_t)WEL * 2;             // bytes per bf16 matrix
  int G = 1;
  {
    size_t need8 = OFF_H4 + (size_t)16384 * IDIM * 2 + 8 * 3 * WELB;
    size_t need2 = OFF_H4 + (size_t)8192  * IDIM * 2 + 2 * 3 * WELB;
    if (ws_size >= need8) G = 8;
    else if (ws_size >= need2) G = 2;
  }
  const size_t h4b = (size_t)((G == 8) ? 16384 : (G == 2 ? 8192 : 4096)) * IDIM * 2;
  unsigned short* h4   = (unsigned short*)(ws + OFF_H4);
  unsigned short* wbuf = (unsigned short*)(ws + OFF_H4 + h4b);

  const int NG = NEXP / G;
  const int NBLK = (128 + G) * NPAN;               // worst-case 1D blocks per group

  hipMemsetAsync(out, 0, (size_t)out_size * sizeof(float), stream);
  hipMemsetAsync(cnt, 0, 512, stream);
  cvt_kernel<<<(T_TOK * HDIM / 8) / 256, 256, 0, stream>>>(x, xb);
  router_kernel<<<T_TOK / 16, 256, 0, stream>>>(x, rw, rb, aff, cnt, lst);
  sched_kernel<<<1, 64, 0, stream>>>(cnt, gbs, ess, gtot, G);

  for (int g = 0; g < NG; ++g) {
    int ge = g * G;
    transpose_group_kernel<<<dim3(45, 45, 3 * G), 256, 0, stream>>>(wg, wu, wd, wbuf, ge);
    gateup_kernel<<<NBLK, 256, 0, stream>>>(
        xb, wbuf, aff, lst, cnt, gbs, ess, gtot + g, h4, ge, G);
    down_kernel<<<NBLK, 256, 0, stream>>>(
        h4, wbuf, out, lst, cnt, gbs, ess, gtot + g, ge, G);
  }
}